// Round 5
// baseline (377.495 us; speedup 1.0000x reference)
//
#include <hip/hip_runtime.h>
#include <cstdint>
#include <cstddef>

// CrossContext: VN attention block. B=4, C=64, N=2048, K=16, fp32.
constexpr int B_ = 4, C_ = 64, N_ = 2048, K_ = 16;
constexpr int D3 = 192;                    // 3*C
constexpr float EPS_ = 1e-6f, BNE_ = 1e-5f, NEG_ = 0.2f;
constexpr size_t S_ = (size_t)B_ * N_ * D3;   // 1,572,864 floats per tensor

// workspace float offsets
// GB bundle: [b][n][4][192] segs {uK,uDk,uV,uDv} -> 3KB contiguous per point
constexpr size_t OFF_PQ  = 0;        // Wq·x   [b][n][192]
constexpr size_t OFF_DQ  = 1*S_;     // Dq·x
constexpr size_t OFF_GB  = 2*S_;     // bundle (4*S_)
constexpr size_t OFF_WK  = 6*S_;     // (Wk2-Wk1)·y  (center parts, [b][n][192])
constexpr size_t OFF_WDK = 7*S_;
constexpr size_t OFF_WV  = 8*S_;
constexpr size_t OFF_WDV = 9*S_;
constexpr size_t OFF_SQ  = 10*S_;                       // B*N
constexpr size_t OFF_ST  = OFF_SQ + (size_t)B_*N_;      // 1024 floats stats
constexpr size_t OFF_IDX = OFF_ST + 1024;               // B*N*K ints
constexpr size_t OFF_DIST= OFF_IDX + (size_t)B_*N_*K_;  // N*N (x4 if ws allows)

__device__ __forceinline__ float wred_sum(float v) {
  #pragma unroll
  for (int off = 32; off > 0; off >>= 1) v += __shfl_xor(v, off, 64);
  return v;
}

// VN BatchNorm(folded scale/shift) + LeakyReLU on one 3-vector. Branchless,
// native rcp/sqrt (1 ulp; output headroom 0.0156 vs 0.109 threshold).
__device__ __forceinline__ void vnlk(float& p0, float& p1, float& p2,
                                     float d0, float d1, float d2,
                                     float s, float sh) {
  float n2 = p0*p0 + p1*p1 + p2*p2;
  float norm = __builtin_amdgcn_sqrtf(n2) + EPS_;
  float f = fmaf(norm, s, sh) * __builtin_amdgcn_rcpf(norm);   // norm_bn/norm
  p0 *= f; p1 *= f; p2 *= f;
  float dot = p0*d0 + p1*d1 + p2*d2;
  float dns = d0*d0 + d1*d1 + d2*d2;
  float g = (1.f - NEG_) * fminf(dot, 0.f) * __builtin_amdgcn_rcpf(dns + EPS_);
  p0 = fmaf(-g, d0, p0); p1 = fmaf(-g, d1, p1); p2 = fmaf(-g, d2, p2);
}

// chnorm scale: p * sc, sc = n/(max(n,1e-12)*max(nch,1e-12))
__device__ __forceinline__ float chnorm_sc(float nc, float nch) {
  return nc * __builtin_amdgcn_rcpf(fmaxf(nc, 1e-12f))
            * __builtin_amdgcn_rcpf(fmaxf(nch, 1e-12f));
}

// ---------------- transforms: out[b][n][o*3+v] = sum_c W[o][c] in[b][c][v][n] --
// rs0: row stride (in floats) of out0 (768 for bundle segs, 192 otherwise).
template<bool PAIR>
__device__ __forceinline__ void do_mm(const float (*ys)[36], const float (*Wl)[129],
                                      float* __restrict__ out0, float* __restrict__ out1,
                                      float* s1s, float* s2s, bool qs,
                                      int og, int ng, int b, int n0, int rs0) {
  float accU[4][2][3] = {};
  float accW[4][2][3] = {};
  #pragma unroll 4
  for (int c = 0; c < 64; ++c) {
    float w1[4], wd[4];
    #pragma unroll
    for (int i = 0; i < 4; ++i) {
      w1[i] = Wl[og*4 + i][c];
      if (PAIR) wd[i] = Wl[og*4 + i][64 + c] - w1[i];
    }
    #pragma unroll
    for (int jj = 0; jj < 2; ++jj)
      #pragma unroll
      for (int v = 0; v < 3; ++v) {
        float yv = ys[c*3 + v][ng*2 + jj];
        #pragma unroll
        for (int i = 0; i < 4; ++i) {
          accU[i][jj][v] = fmaf(w1[i], yv, accU[i][jj][v]);
          if (PAIR) accW[i][jj][v] = fmaf(wd[i], yv, accW[i][jj][v]);
        }
      }
  }
  #pragma unroll
  for (int jj = 0; jj < 2; ++jj) {
    int n = n0 + ng*2 + jj;
    size_t base0 = ((size_t)b*N_ + n)*rs0 + og*12;
    alignas(16) float tmp[12];
    #pragma unroll
    for (int i = 0; i < 4; ++i)
      #pragma unroll
      for (int v = 0; v < 3; ++v) tmp[i*3+v] = accU[i][jj][v];
    float4* dst = (float4*)(out0 + base0);
    dst[0] = ((float4*)tmp)[0]; dst[1] = ((float4*)tmp)[1]; dst[2] = ((float4*)tmp)[2];
    if (PAIR) {
      size_t base1 = ((size_t)b*N_ + n)*D3 + og*12;
      #pragma unroll
      for (int i = 0; i < 4; ++i)
        #pragma unroll
        for (int v = 0; v < 3; ++v) tmp[i*3+v] = accW[i][jj][v];
      float4* dst1 = (float4*)(out1 + base1);
      dst1[0] = ((float4*)tmp)[0]; dst1[1] = ((float4*)tmp)[1]; dst1[2] = ((float4*)tmp)[2];
    }
  }
  if (!PAIR && qs) {    // fold Q-branch BN stats in (pre-BN norms of p)
    #pragma unroll
    for (int i = 0; i < 4; ++i) {
      float a = 0.f, b2 = 0.f;
      #pragma unroll
      for (int jj = 0; jj < 2; ++jj) {
        float nn = sqrtf(accU[i][jj][0]*accU[i][jj][0] + accU[i][jj][1]*accU[i][jj][1]
                       + accU[i][jj][2]*accU[i][jj][2]) + EPS_;
        a += nn; b2 += nn*nn;
      }
      atomicAdd(&s1s[og*4 + i], a);
      atomicAdd(&s2s[og*4 + i], b2);
    }
  }
}

// grid (N/32, B, 6): z in {Wq·x, Dq·x, Wk·y, Dk·y, Wv·y, Dv·y}
__global__ __launch_bounds__(256) void transform_kernel(
    const float* __restrict__ x, const float* __restrict__ y,
    const float* __restrict__ Wq, const float* __restrict__ Dq,
    const float* __restrict__ Wk, const float* __restrict__ Dk,
    const float* __restrict__ Wv, const float* __restrict__ Dv,
    float* __restrict__ ws) {
  __shared__ float ys[D3][36];
  __shared__ float Wl[64][129];
  __shared__ float s1s[64], s2s[64];
  int t = threadIdx.x, n0 = blockIdx.x*32, b = blockIdx.y, z = blockIdx.z;
  const bool isx = (z < 2);
  const float* in = (isx ? x : y) + (size_t)b*D3*N_;
  #pragma unroll
  for (int i = 0; i < 6; ++i) {           // 192*32/4/256
    int lin = t + i*256;
    int d = lin >> 3, c4 = (lin & 7)*4;
    *(float4*)&ys[d][c4] = *(const float4*)&in[(size_t)d*N_ + n0 + c4];
  }
  const float* Wg = (z==0)?Wq:(z==1)?Dq:(z==2)?Wk:(z==3)?Dk:(z==4)?Wv:Dv;
  if (isx) { for (int i = t; i < 4096; i += 256) Wl[i>>6][i&63] = Wg[i]; }
  else     { for (int i = t; i < 8192; i += 256) Wl[i>>7][i&127] = Wg[i]; }
  if (z == 0 && t < 64) { s1s[t] = 0.f; s2s[t] = 0.f; }
  __syncthreads();
  if (z == 2 && t < 32) {                 // sq for kNN (d ascending, matches ref)
    float s = 0.f;
    for (int d = 0; d < D3; ++d) { float v = ys[d][t]; s += v*v; }
    ws[OFF_SQ + (size_t)b*N_ + n0 + t] = s;
  }
  int og = t & 15, ng = t >> 4;
  float* st = ws + OFF_ST;
  if (isx) {
    float* out0 = ws + (z ? OFF_DQ : OFF_PQ);
    do_mm<false>(ys, Wl, out0, nullptr, s1s, s2s, z == 0, og, ng, b, n0, D3);
    if (z == 0) {
      __syncthreads();
      if (t < 64) { atomicAdd(&st[t], s1s[t]); atomicAdd(&st[64 + t], s2s[t]); }
    }
  } else {
    int seg = z - 2;                      // 0..3: uK,uDk,uV,uDv
    float* out0 = ws + OFF_GB + (size_t)seg*192;
    float* out1 = ws + ((z==2)?OFF_WK:(z==3)?OFF_WDK:(z==4)?OFF_WV:OFF_WDV);
    do_mm<true>(ys, Wl, out0, out1, nullptr, nullptr, false, og, ng, b, n0, 768);
  }
}

// ---------------- kNN dist: 64n x 128m tile, batched in z ----------------------
// grid (N/128, N/64, nb), block 256. dist[n][m] = 2*dot - sq[n] - sq[m].
// Register-prefetch pipeline: dt+1 global loads issue before dt's FMA loop.
// FP accumulation order identical to prior passing rounds (dd ascending).
__global__ __launch_bounds__(256) void dist_kernel(const float* __restrict__ y,
                                                   float* __restrict__ ws,
                                                   int b0, size_t dstride) {
  __shared__ float As[32][68];            // 64 n cols
  __shared__ float Bs[32][136];           // 128 m cols
  int b = b0 + blockIdx.z;
  const float* yb = y + (size_t)b * D3 * N_;      // [192][N]
  const float* sq = ws + OFF_SQ + (size_t)b * N_;
  float* dist = ws + OFF_DIST + dstride * blockIdx.z;
  int t = threadIdx.x;
  int m0 = blockIdx.x * 128, n0 = blockIdx.y * 64;
  int tm = t & 15, tn = t >> 4;           // 16 m-groups x 16 n-groups
  float acc[4][8] = {};                   // 4 n x (4 m + 4 m at +64)
  float4 pa[2], pb[4];
  #pragma unroll
  for (int i = 0; i < 2; ++i) {           // prefetch dt=0
    int idx = t + i*256;
    pa[i] = *(const float4*)&yb[(size_t)(idx >> 4)*N_ + n0 + (idx & 15)*4];
  }
  #pragma unroll
  for (int i = 0; i < 4; ++i) {
    int idx = t + i*256;
    pb[i] = *(const float4*)&yb[(size_t)(idx >> 5)*N_ + m0 + (idx & 31)*4];
  }
  for (int dt = 0; dt < 6; ++dt) {
    __syncthreads();                      // consumers done with LDS
    #pragma unroll
    for (int i = 0; i < 2; ++i) {
      int idx = t + i*256;
      *(float4*)&As[idx >> 4][(idx & 15)*4] = pa[i];
    }
    #pragma unroll
    for (int i = 0; i < 4; ++i) {
      int idx = t + i*256;
      *(float4*)&Bs[idx >> 5][(idx & 31)*4] = pb[i];
    }
    __syncthreads();                      // LDS ready
    if (dt < 5) {                         // issue dt+1 loads; hide under FMAs
      #pragma unroll
      for (int i = 0; i < 2; ++i) {
        int idx = t + i*256;
        pa[i] = *(const float4*)&yb[(size_t)((dt+1)*32 + (idx >> 4))*N_ + n0 + (idx & 15)*4];
      }
      #pragma unroll
      for (int i = 0; i < 4; ++i) {
        int idx = t + i*256;
        pb[i] = *(const float4*)&yb[(size_t)((dt+1)*32 + (idx >> 5))*N_ + m0 + (idx & 31)*4];
      }
    }
    #pragma unroll 8
    for (int dd = 0; dd < 32; ++dd) {
      float4 a4 = *(float4*)&As[dd][tn*4];
      float4 b4 = *(float4*)&Bs[dd][tm*4];        // 2-way bank alias: free
      float4 c4 = *(float4*)&Bs[dd][64 + tm*4];   // 2-way bank alias: free
      float ar[4] = {a4.x, a4.y, a4.z, a4.w};
      float b0v[4] = {b4.x, b4.y, b4.z, b4.w};
      float b1v[4] = {c4.x, c4.y, c4.z, c4.w};
      #pragma unroll
      for (int j = 0; j < 4; ++j) {
        #pragma unroll
        for (int i = 0; i < 4; ++i) {
          acc[j][i]   = fmaf(ar[j], b0v[i], acc[j][i]);
          acc[j][4+i] = fmaf(ar[j], b1v[i], acc[j][4+i]);
        }
      }
    }
  }
  float4 s0 = *(const float4*)&sq[m0 + tm*4];
  float4 s1 = *(const float4*)&sq[m0 + 64 + tm*4];
  float sm0[4] = {s0.x, s0.y, s0.z, s0.w};
  float sm1[4] = {s1.x, s1.y, s1.z, s1.w};
  #pragma unroll
  for (int j = 0; j < 4; ++j) {
    float sn = sq[n0 + tn*4 + j];
    float4 r0, r1;
    r0.x = 2.f*acc[j][0] - sn - sm0[0]; r0.y = 2.f*acc[j][1] - sn - sm0[1];
    r0.z = 2.f*acc[j][2] - sn - sm0[2]; r0.w = 2.f*acc[j][3] - sn - sm0[3];
    r1.x = 2.f*acc[j][4] - sn - sm1[0]; r1.y = 2.f*acc[j][5] - sn - sm1[1];
    r1.z = 2.f*acc[j][6] - sn - sm1[2]; r1.w = 2.f*acc[j][7] - sn - sm1[3];
    size_t rowb = (size_t)(n0 + tn*4 + j)*N_ + m0 + tm*4;
    *(float4*)&dist[rowb]      = r0;
    *(float4*)&dist[rowb + 64] = r1;
  }
}

// grid (N/4, nb), block 256: ONE WAVE PER ROW, no barriers. Each lane holds 32
// elements (m = j*64 + lane) in registers; 16x {local argmax, butterfly argmax
// with (value desc, m asc) order, predicated winner mask}. Matches jax top_k.
__global__ __launch_bounds__(256) void topk_kernel(const float* __restrict__ ws_c,
                                                   int* __restrict__ idxo,
                                                   int b0, size_t dstride) {
  int t = threadIdx.x;
  int w = t >> 6, l = t & 63;
  int n = blockIdx.x*4 + w;
  int b = b0 + blockIdx.y;
  const float* dr = ws_c + OFF_DIST + dstride*blockIdx.y + (size_t)n * N_;
  float v[32];
  #pragma unroll
  for (int j = 0; j < 32; ++j) v[j] = dr[j*64 + l];
  int mine = 0;
  for (int it = 0; it < K_; ++it) {
    float bv = v[0]; int bj = 0;
    #pragma unroll
    for (int j = 1; j < 32; ++j) {
      bool g = v[j] > bv;
      bv = g ? v[j] : bv;
      bj = g ? j : bj;
    }
    int bm = bj*64 + l;
    #pragma unroll
    for (int off = 32; off > 0; off >>= 1) {
      float ov = __shfl_xor(bv, off, 64);
      int   om = __shfl_xor(bm, off, 64);
      if (ov > bv || (ov == bv && om < bm)) { bv = ov; bm = om; }
    }
    if (l == it) mine = bm;
    int wj = bm >> 6, wl = bm & 63;
    #pragma unroll
    for (int j = 0; j < 32; ++j)
      v[j] = (j == wj && l == wl) ? -3.4e38f : v[j];
  }
  if (l < K_) idxo[((size_t)b*N_ + n)*K_ + l] = mine;
}

// grid (N*K/128, B), block 256: K- and V-branch norm stats (gathered bundle).
__global__ __launch_bounds__(256) void kvstats_kernel(float* __restrict__ ws,
                                                      const int* __restrict__ idxp) {
  int t = threadIdx.x, o = t & 63, eg = t >> 6;
  int e0 = blockIdx.x * 128, b = blockIdx.y;
  const float* GB = ws + OFF_GB;
  const float* wK = ws + OFF_WK; const float* wV = ws + OFF_WV;
  int bN = b * N_;
  float k1 = 0.f, k2 = 0.f, v1 = 0.f, v2 = 0.f;
  for (int j = 0; j < 32; ++j) {
    int e = e0 + eg + j*4;
    int n = e >> 4, kk = e & 15;
    int m = idxp[(bN + n)*K_ + kk];
    int rb = (bN + n)*D3 + o*3;
    size_t gb = (size_t)(bN + m)*768 + o*3;      // bundle: seg0=uK, seg2=uV
    float p0 = GB[gb] + wK[rb], p1 = GB[gb+1] + wK[rb+1], p2 = GB[gb+2] + wK[rb+2];
    float nk = __builtin_amdgcn_sqrtf(p0*p0 + p1*p1 + p2*p2) + EPS_;
    k1 += nk; k2 += nk*nk;
    float q0 = GB[gb+384] + wV[rb], q1 = GB[gb+385] + wV[rb+1], q2 = GB[gb+386] + wV[rb+2];
    float nv = __builtin_amdgcn_sqrtf(q0*q0 + q1*q1 + q2*q2) + EPS_;
    v1 += nv; v2 += nv*nv;
  }
  __shared__ float red[4][256];
  red[0][t] = k1; red[1][t] = k2; red[2][t] = v1; red[3][t] = v2;
  __syncthreads();
  if (t < 64) {
    float* st = ws + OFF_ST;
    float a = red[0][t] + red[0][t+64] + red[0][t+128] + red[0][t+192];
    atomicAdd(&st[128 + t], a);
    a = red[1][t] + red[1][t+64] + red[1][t+128] + red[1][t+192];
    atomicAdd(&st[192 + t], a);
    a = red[2][t] + red[2][t+64] + red[2][t+128] + red[2][t+192];
    atomicAdd(&st[256 + t], a);
    a = red[3][t] + red[3][t+64] + red[3][t+128] + red[3][t+192];
    atomicAdd(&st[320 + t], a);
  }
}

// grid (N/4, B), block 256: wave w owns point n = bx*4+w, lane = channel o.
// BN fold inline (from raw sums). Pass A: K branch over 16 neighbors -> qk;
// softmax in regs; Pass B: V branch, weighted accumulate; float4 epilogue.
__global__ __launch_bounds__(256, 2) void final_kernel(const float* __restrict__ x,
                                                       const float* __restrict__ ws_c,
                                                       const int* __restrict__ idxp,
                                                       const float* __restrict__ gq,
                                                       const float* __restrict__ bq,
                                                       const float* __restrict__ gk,
                                                       const float* __restrict__ bk,
                                                       const float* __restrict__ gv,
                                                       const float* __restrict__ bv,
                                                       float* __restrict__ out) {
  const float* pq  = ws_c + OFF_PQ;  const float* dq  = ws_c + OFF_DQ;
  const float* GB  = ws_c + OFF_GB;
  const float* wK  = ws_c + OFF_WK;  const float* wDk = ws_c + OFF_WDK;
  const float* wV  = ws_c + OFF_WV;  const float* wDv = ws_c + OFF_WDV;
  const float* st  = ws_c + OFF_ST;
  int t = threadIdx.x, o = t & 63, w = t >> 6;
  int n0 = blockIdx.x*4, n = n0 + w, b = blockIdx.y;
  int bN = b * N_;
  __shared__ float ob2[192][5];           // [c*3+v][n-slot], stride 5
  // fold BN scale/shift from raw sums (redundant per wave; ~30 VALU)
  float sQ, shQ, sK, shK, sV, shV;
  {
    const float icq = 1.f / (float)(B_ * N_);
    float mu = st[o] * icq;
    float var = fmaxf(st[64+o]*icq - mu*mu, 0.f);
    sQ = gq[o] * rsqrtf(var + BNE_); shQ = bq[o] - mu*sQ;
    const float ick = 1.f / (float)(B_ * N_ * K_);
    mu = st[128+o] * ick;
    var = fmaxf(st[192+o]*ick - mu*mu, 0.f);
    sK = gk[o] * rsqrtf(var + BNE_); shK = bk[o] - mu*sK;
    mu = st[256+o] * ick;
    var = fmaxf(st[320+o]*ick - mu*mu, 0.f);
    sV = gv[o] * rsqrtf(var + BNE_); shV = bv[o] - mu*sV;
  }
  // neighbor indices (wave-uniform -> broadcast loads)
  int mi[16];
  {
    const int* ip = idxp + (size_t)(bN + n)*K_;
    int4 a0 = *(const int4*)&ip[0];  mi[0]=a0.x;  mi[1]=a0.y;  mi[2]=a0.z;  mi[3]=a0.w;
    int4 a1 = *(const int4*)&ip[4];  mi[4]=a1.x;  mi[5]=a1.y;  mi[6]=a1.z;  mi[7]=a1.w;
    int4 a2 = *(const int4*)&ip[8];  mi[8]=a2.x;  mi[9]=a2.y;  mi[10]=a2.z; mi[11]=a2.w;
    int4 a3 = *(const int4*)&ip[12]; mi[12]=a3.x; mi[13]=a3.y; mi[14]=a3.z; mi[15]=a3.w;
  }
  int rb = (bN + n)*D3 + o*3;
  // Q branch (once per n)
  float q0 = pq[rb], q1 = pq[rb+1], q2 = pq[rb+2];
  float e0 = dq[rb], e1 = dq[rb+1], e2 = dq[rb+2];
  vnlk(q0, q1, q2, e0, e1, e2, sQ, shQ);
  float qn2 = q0*q0 + q1*q1 + q2*q2;
  float qsc = chnorm_sc(__builtin_amdgcn_sqrtf(qn2),
                        __builtin_amdgcn_sqrtf(wred_sum(qn2)));
  float qx0 = q0*qsc, qx1 = q1*qsc, qx2 = q2*qsc;
  float wk0 = wK[rb],  wk1 = wK[rb+1],  wk2 = wK[rb+2];
  float wdk0= wDk[rb], wdk1= wDk[rb+1], wdk2= wDk[rb+2];
  const float isq = 0.07216878364870323f;   // 1/sqrt(3*C)
  // ---- pass A: K branch -> qk[16]  (bundle seg0=uK, seg1=uDk)
  float qk[16];
  #pragma unroll
  for (int kk = 0; kk < 16; ++kk) {
    size_t gb = (size_t)(bN + mi[kk])*768 + o*3;
    float p0 = GB[gb]     + wk0, p1 = GB[gb+1]   + wk1, p2 = GB[gb+2]   + wk2;
    float f0 = GB[gb+192] + wdk0, f1 = GB[gb+193] + wdk1, f2 = GB[gb+194] + wdk2;
    vnlk(p0, p1, p2, f0, f1, f2, sK, shK);
    float nc2 = p0*p0 + p1*p1 + p2*p2;
    float sc = chnorm_sc(__builtin_amdgcn_sqrtf(nc2),
                         __builtin_amdgcn_sqrtf(wred_sum(nc2)));
    qk[kk] = (p0*qx0 + p1*qx1 + p2*qx2) * (sc * isq);
  }
  // ---- softmax over 16 in registers
  float mx = qk[0];
  #pragma unroll
  for (int kk = 1; kk < 16; ++kk) mx = fmaxf(mx, qk[kk]);
  float se = 0.f;
  #pragma unroll
  for (int kk = 0; kk < 16; ++kk) { float e = __expf(qk[kk] - mx); qk[kk] = e; se += e; }
  float inv = __builtin_amdgcn_rcpf(se);
  // ---- pass B: V branch (bundle seg2=uV, seg3=uDv), weighted accumulate
  float wv0 = wV[rb],  wv1 = wV[rb+1],  wv2 = wV[rb+2];
  float wdv0= wDv[rb], wdv1= wDv[rb+1], wdv2= wDv[rb+2];
  float a0 = 0.f, a1 = 0.f, a2 = 0.f;
  #pragma unroll
  for (int kk = 0; kk < 16; ++kk) {
    size_t gb = (size_t)(bN + mi[kk])*768 + o*3;
    float v0 = GB[gb+384] + wv0, v1 = GB[gb+385] + wv1, v2 = GB[gb+386] + wv2;
    float g0 = GB[gb+576] + wdv0, g1 = GB[gb+577] + wdv1, g2 = GB[gb+578] + wdv2;
    vnlk(v0, v1, v2, g0, g1, g2, sV, shV);
    float at = qk[kk] * inv;
    a0 = fmaf(at, v0, a0); a1 = fmaf(at, v1, a1); a2 = fmaf(at, v2, a2);
  }
  ob2[o*3 + 0][w] = a0;
  ob2[o*3 + 1][w] = a1;
  ob2[o*3 + 2][w] = a2;
  __syncthreads();
  if (t < 192) {                          // t == c*3+v; 4 consecutive n per row
    size_t xo = ((size_t)b*D3 + t)*N_ + n0;
    float4 xr = *(const float4*)&x[xo];
    float4 r;
    r.x = xr.x + ob2[t][0]; r.y = xr.y + ob2[t][1];
    r.z = xr.z + ob2[t][2]; r.w = xr.w + ob2[t][3];
    *(float4*)&out[xo] = r;
  }
}

extern "C" void kernel_launch(void* const* d_in, const int* in_sizes, int n_in,
                              void* d_out, int out_size, void* d_ws, size_t ws_size,
                              hipStream_t stream) {
  const float* x  = (const float*)d_in[0];
  const float* y  = (const float*)d_in[1];
  const float* Wq = (const float*)d_in[2];
  const float* Dq = (const float*)d_in[3];
  const float* gq = (const float*)d_in[4];
  const float* bq = (const float*)d_in[5];
  const float* Wk = (const float*)d_in[6];
  const float* Dk = (const float*)d_in[7];
  const float* gk = (const float*)d_in[8];
  const float* bk = (const float*)d_in[9];
  const float* Wv = (const float*)d_in[10];
  const float* Dv = (const float*)d_in[11];
  const float* gv = (const float*)d_in[12];
  const float* bv = (const float*)d_in[13];
  float* ws = (float*)d_ws;
  float* out = (float*)d_out;
  int* idxp = (int*)(ws + OFF_IDX);

  // batched kNN if the workspace can hold B full NxN dist buffers (~130 MB)
  const size_t need = (OFF_DIST + (size_t)B_*N_*N_) * sizeof(float);
  const bool batched = ws_size >= need;

  hipMemsetAsync((void*)(ws + OFF_ST), 0, 1024 * sizeof(float), stream);
  transform_kernel<<<dim3(N_/32, B_, 6), 256, 0, stream>>>(x, y, Wq, Dq, Wk, Dk, Wv, Dv, ws);
  if (batched) {
    dist_kernel<<<dim3(N_/128, N_/64, B_), 256, 0, stream>>>(y, ws, 0, (size_t)N_*N_);
    topk_kernel<<<dim3(N_/4, B_), 256, 0, stream>>>(ws, idxp, 0, (size_t)N_*N_);
  } else {
    for (int b = 0; b < B_; ++b) {
      dist_kernel<<<dim3(N_/128, N_/64, 1), 256, 0, stream>>>(y, ws, b, 0);
      topk_kernel<<<dim3(N_/4, 1), 256, 0, stream>>>(ws, idxp, b, 0);
    }
  }
  kvstats_kernel<<<dim3(N_*K_/128, B_), 256, 0, stream>>>(ws, idxp);
  final_kernel<<<dim3(N_/4, B_), 256, 0, stream>>>(x, ws, idxp, gq, bq, gk, bk, gv, bv, out);
}

// Round 6
// 357.470 us; speedup vs baseline: 1.0560x; 1.0560x over previous
//
#include <hip/hip_runtime.h>
#include <cstdint>
#include <cstddef>

// CrossContext: VN attention block. B=4, C=64, N=2048, K=16, fp32.
constexpr int B_ = 4, C_ = 64, N_ = 2048, K_ = 16;
constexpr int D3 = 192;                    // 3*C
constexpr float EPS_ = 1e-6f, BNE_ = 1e-5f, NEG_ = 0.2f;
constexpr size_t S_ = (size_t)B_ * N_ * D3;   // 1,572,864 floats per tensor

// workspace float offsets
// GB bundle: [b][n][4][192] segs {uK,uDk,uV,uDv} -> 3KB contiguous per point
constexpr size_t OFF_PQ  = 0;        // Wq·x   [b][n][192]
constexpr size_t OFF_DQ  = 1*S_;     // Dq·x
constexpr size_t OFF_GB  = 2*S_;     // bundle (4*S_)
constexpr size_t OFF_WK  = 6*S_;     // (Wk2-Wk1)·y  (center parts, [b][n][192])
constexpr size_t OFF_WDK = 7*S_;
constexpr size_t OFF_WV  = 8*S_;
constexpr size_t OFF_WDV = 9*S_;
constexpr size_t OFF_SQ  = 10*S_;                       // B*N
constexpr size_t OFF_ST  = OFF_SQ + (size_t)B_*N_;      // 1024 floats stats
constexpr size_t OFF_IDX = OFF_ST + 1024;               // B*N*K ints
constexpr size_t OFF_DIST= OFF_IDX + (size_t)B_*N_*K_;  // N*N (x4 if ws allows)

__device__ __forceinline__ float wred_sum(float v) {
  #pragma unroll
  for (int off = 32; off > 0; off >>= 1) v += __shfl_xor(v, off, 64);
  return v;
}

// async global->LDS, 16B per lane. LDS dest must be linear: base + lane*16.
__device__ __forceinline__ void gld_lds16(const float* g, float* l) {
  __builtin_amdgcn_global_load_lds(
      (const __attribute__((address_space(1))) void*)g,
      (__attribute__((address_space(3))) void*)l, 16, 0, 0);
}

// VN BatchNorm(folded scale/shift) + LeakyReLU on one 3-vector. Branchless,
// native rcp/sqrt (1 ulp; output headroom 0.0156 vs 0.109 threshold).
__device__ __forceinline__ void vnlk(float& p0, float& p1, float& p2,
                                     float d0, float d1, float d2,
                                     float s, float sh) {
  float n2 = p0*p0 + p1*p1 + p2*p2;
  float norm = __builtin_amdgcn_sqrtf(n2) + EPS_;
  float f = fmaf(norm, s, sh) * __builtin_amdgcn_rcpf(norm);   // norm_bn/norm
  p0 *= f; p1 *= f; p2 *= f;
  float dot = p0*d0 + p1*d1 + p2*d2;
  float dns = d0*d0 + d1*d1 + d2*d2;
  float g = (1.f - NEG_) * fminf(dot, 0.f) * __builtin_amdgcn_rcpf(dns + EPS_);
  p0 = fmaf(-g, d0, p0); p1 = fmaf(-g, d1, p1); p2 = fmaf(-g, d2, p2);
}

// chnorm scale: p * sc, sc = n/(max(n,1e-12)*max(nch,1e-12))
__device__ __forceinline__ float chnorm_sc(float nc, float nch) {
  return nc * __builtin_amdgcn_rcpf(fmaxf(nc, 1e-12f))
            * __builtin_amdgcn_rcpf(fmaxf(nch, 1e-12f));
}

// ---------------- transforms: out[b][n][o*3+v] = sum_c W[o][c] in[b][c][v][n] --
// rs0: row stride (in floats) of out0 (768 for bundle segs, 192 otherwise).
template<bool PAIR>
__device__ __forceinline__ void do_mm(const float (*ys)[36], const float (*Wl)[129],
                                      float* __restrict__ out0, float* __restrict__ out1,
                                      float* s1s, float* s2s, bool qs,
                                      int og, int ng, int b, int n0, int rs0) {
  float accU[4][2][3] = {};
  float accW[4][2][3] = {};
  #pragma unroll 4
  for (int c = 0; c < 64; ++c) {
    float w1[4], wd[4];
    #pragma unroll
    for (int i = 0; i < 4; ++i) {
      w1[i] = Wl[og*4 + i][c];
      if (PAIR) wd[i] = Wl[og*4 + i][64 + c] - w1[i];
    }
    #pragma unroll
    for (int jj = 0; jj < 2; ++jj)
      #pragma unroll
      for (int v = 0; v < 3; ++v) {
        float yv = ys[c*3 + v][ng*2 + jj];
        #pragma unroll
        for (int i = 0; i < 4; ++i) {
          accU[i][jj][v] = fmaf(w1[i], yv, accU[i][jj][v]);
          if (PAIR) accW[i][jj][v] = fmaf(wd[i], yv, accW[i][jj][v]);
        }
      }
  }
  #pragma unroll
  for (int jj = 0; jj < 2; ++jj) {
    int n = n0 + ng*2 + jj;
    size_t base0 = ((size_t)b*N_ + n)*rs0 + og*12;
    alignas(16) float tmp[12];
    #pragma unroll
    for (int i = 0; i < 4; ++i)
      #pragma unroll
      for (int v = 0; v < 3; ++v) tmp[i*3+v] = accU[i][jj][v];
    float4* dst = (float4*)(out0 + base0);
    dst[0] = ((float4*)tmp)[0]; dst[1] = ((float4*)tmp)[1]; dst[2] = ((float4*)tmp)[2];
    if (PAIR) {
      size_t base1 = ((size_t)b*N_ + n)*D3 + og*12;
      #pragma unroll
      for (int i = 0; i < 4; ++i)
        #pragma unroll
        for (int v = 0; v < 3; ++v) tmp[i*3+v] = accW[i][jj][v];
      float4* dst1 = (float4*)(out1 + base1);
      dst1[0] = ((float4*)tmp)[0]; dst1[1] = ((float4*)tmp)[1]; dst1[2] = ((float4*)tmp)[2];
    }
  }
  if (!PAIR && qs) {    // fold Q-branch BN stats in (pre-BN norms of p)
    #pragma unroll
    for (int i = 0; i < 4; ++i) {
      float a = 0.f, b2 = 0.f;
      #pragma unroll
      for (int jj = 0; jj < 2; ++jj) {
        float nn = sqrtf(accU[i][jj][0]*accU[i][jj][0] + accU[i][jj][1]*accU[i][jj][1]
                       + accU[i][jj][2]*accU[i][jj][2]) + EPS_;
        a += nn; b2 += nn*nn;
      }
      atomicAdd(&s1s[og*4 + i], a);
      atomicAdd(&s2s[og*4 + i], b2);
    }
  }
}

// grid (N/32, B, 6): z in {Wq·x, Dq·x, Wk·y, Dk·y, Wv·y, Dv·y}
__global__ __launch_bounds__(256) void transform_kernel(
    const float* __restrict__ x, const float* __restrict__ y,
    const float* __restrict__ Wq, const float* __restrict__ Dq,
    const float* __restrict__ Wk, const float* __restrict__ Dk,
    const float* __restrict__ Wv, const float* __restrict__ Dv,
    float* __restrict__ ws) {
  __shared__ float ys[D3][36];
  __shared__ float Wl[64][129];
  __shared__ float s1s[64], s2s[64];
  int t = threadIdx.x, n0 = blockIdx.x*32, b = blockIdx.y, z = blockIdx.z;
  const bool isx = (z < 2);
  const float* in = (isx ? x : y) + (size_t)b*D3*N_;
  #pragma unroll
  for (int i = 0; i < 6; ++i) {           // 192*32/4/256
    int lin = t + i*256;
    int d = lin >> 3, c4 = (lin & 7)*4;
    *(float4*)&ys[d][c4] = *(const float4*)&in[(size_t)d*N_ + n0 + c4];
  }
  const float* Wg = (z==0)?Wq:(z==1)?Dq:(z==2)?Wk:(z==3)?Dk:(z==4)?Wv:Dv;
  if (isx) { for (int i = t; i < 4096; i += 256) Wl[i>>6][i&63] = Wg[i]; }
  else     { for (int i = t; i < 8192; i += 256) Wl[i>>7][i&127] = Wg[i]; }
  if (z == 0 && t < 64) { s1s[t] = 0.f; s2s[t] = 0.f; }
  __syncthreads();
  if (z == 2 && t < 32) {                 // sq for kNN (d ascending, matches ref)
    float s = 0.f;
    for (int d = 0; d < D3; ++d) { float v = ys[d][t]; s += v*v; }
    ws[OFF_SQ + (size_t)b*N_ + n0 + t] = s;
  }
  int og = t & 15, ng = t >> 4;
  float* st = ws + OFF_ST;
  if (isx) {
    float* out0 = ws + (z ? OFF_DQ : OFF_PQ);
    do_mm<false>(ys, Wl, out0, nullptr, s1s, s2s, z == 0, og, ng, b, n0, D3);
    if (z == 0) {
      __syncthreads();
      if (t < 64) { atomicAdd(&st[t], s1s[t]); atomicAdd(&st[64 + t], s2s[t]); }
    }
  } else {
    int seg = z - 2;                      // 0..3: uK,uDk,uV,uDv
    float* out0 = ws + OFF_GB + (size_t)seg*192;
    float* out1 = ws + ((z==2)?OFF_WK:(z==3)?OFF_WDK:(z==4)?OFF_WV:OFF_WDV);
    do_mm<true>(ys, Wl, out0, out1, nullptr, nullptr, false, og, ng, b, n0, 768);
  }
}

// ---------------- kNN dist: 64n x 128m tile, async LDS double-buffer ----------
// grid (N/128, N/64, nb), block 256. dist[n][m] = 2*dot - sq[n] - sq[m].
// global_load_lds (16B) stages tile dt+1 while FMAs consume tile dt; the
// __syncthreads() implicit vmcnt(0) drain lands AFTER the 2048-cycle FMA loop.
// FP accumulation order identical to prior passing rounds (dd ascending).
__global__ __launch_bounds__(256) void dist_kernel(const float* __restrict__ y,
                                                   float* __restrict__ ws,
                                                   int b0, size_t dstride) {
  __shared__ float As[2][2048];           // [32][64] linear (gload_lds needs linear)
  __shared__ float Bs[2][4096];           // [32][128] linear
  int b = b0 + blockIdx.z;
  const float* yb = y + (size_t)b * D3 * N_;      // [192][N]
  const float* sq = ws + OFF_SQ + (size_t)b * N_;
  float* dist = ws + OFF_DIST + dstride * blockIdx.z;
  int t = threadIdx.x;
  int m0 = blockIdx.x * 128, n0 = blockIdx.y * 64;
  int tm = t & 15, tn = t >> 4;           // 16 m-groups x 16 n-groups

  auto stage = [&](int buf, int dt) {
    #pragma unroll
    for (int j = 0; j < 2; ++j) {         // As: 512 float4
      int idx = j*256 + t;
      gld_lds16(&yb[(size_t)(dt*32 + (idx >> 4))*N_ + n0 + (idx & 15)*4],
                &As[buf][idx*4]);
    }
    #pragma unroll
    for (int j = 0; j < 4; ++j) {         // Bs: 1024 float4
      int idx = j*256 + t;
      gld_lds16(&yb[(size_t)(dt*32 + (idx >> 5))*N_ + m0 + (idx & 31)*4],
                &Bs[buf][idx*4]);
    }
  };

  float acc[4][8] = {};                   // 4 n x (4 m + 4 m at +64)
  stage(0, 0);
  __syncthreads();                        // drain vmcnt -> buf0 ready
  int cur = 0;
  for (int dt = 0; dt < 6; ++dt) {
    if (dt < 5) stage(cur ^ 1, dt + 1);   // async: in flight during FMAs
    const float* Ac = As[cur];
    const float* Bc = Bs[cur];
    #pragma unroll 8
    for (int dd = 0; dd < 32; ++dd) {
      float4 a4 = *(const float4*)&Ac[dd*64 + tn*4];
      float4 b4 = *(const float4*)&Bc[dd*128 + tm*4];
      float4 c4 = *(const float4*)&Bc[dd*128 + 64 + tm*4];
      float ar[4] = {a4.x, a4.y, a4.z, a4.w};
      float b0v[4] = {b4.x, b4.y, b4.z, b4.w};
      float b1v[4] = {c4.x, c4.y, c4.z, c4.w};
      #pragma unroll
      for (int j = 0; j < 4; ++j) {
        #pragma unroll
        for (int i = 0; i < 4; ++i) {
          acc[j][i]   = fmaf(ar[j], b0v[i], acc[j][i]);
          acc[j][4+i] = fmaf(ar[j], b1v[i], acc[j][4+i]);
        }
      }
    }
    __syncthreads();                      // drains this iter's stage; swap safe
    cur ^= 1;
  }
  float4 s0 = *(const float4*)&sq[m0 + tm*4];
  float4 s1 = *(const float4*)&sq[m0 + 64 + tm*4];
  float sm0[4] = {s0.x, s0.y, s0.z, s0.w};
  float sm1[4] = {s1.x, s1.y, s1.z, s1.w};
  #pragma unroll
  for (int j = 0; j < 4; ++j) {
    float sn = sq[n0 + tn*4 + j];
    float4 r0, r1;
    r0.x = 2.f*acc[j][0] - sn - sm0[0]; r0.y = 2.f*acc[j][1] - sn - sm0[1];
    r0.z = 2.f*acc[j][2] - sn - sm0[2]; r0.w = 2.f*acc[j][3] - sn - sm0[3];
    r1.x = 2.f*acc[j][4] - sn - sm1[0]; r1.y = 2.f*acc[j][5] - sn - sm1[1];
    r1.z = 2.f*acc[j][6] - sn - sm1[2]; r1.w = 2.f*acc[j][7] - sn - sm1[3];
    size_t rowb = (size_t)(n0 + tn*4 + j)*N_ + m0 + tm*4;
    *(float4*)&dist[rowb]      = r0;
    *(float4*)&dist[rowb + 64] = r1;
  }
}

// grid (N/4, nb), block 256: ONE WAVE PER ROW, no barriers. Each lane holds 32
// elements (m = j*64 + lane) in registers; 16x {local argmax, butterfly argmax
// with (value desc, m asc) order, predicated winner mask}. Matches jax top_k.
__global__ __launch_bounds__(256) void topk_kernel(const float* __restrict__ ws_c,
                                                   int* __restrict__ idxo,
                                                   int b0, size_t dstride) {
  int t = threadIdx.x;
  int w = t >> 6, l = t & 63;
  int n = blockIdx.x*4 + w;
  int b = b0 + blockIdx.y;
  const float* dr = ws_c + OFF_DIST + dstride*blockIdx.y + (size_t)n * N_;
  float v[32];
  #pragma unroll
  for (int j = 0; j < 32; ++j) v[j] = dr[j*64 + l];
  int mine = 0;
  for (int it = 0; it < K_; ++it) {
    float bv = v[0]; int bj = 0;
    #pragma unroll
    for (int j = 1; j < 32; ++j) {
      bool g = v[j] > bv;
      bv = g ? v[j] : bv;
      bj = g ? j : bj;
    }
    int bm = bj*64 + l;
    #pragma unroll
    for (int off = 32; off > 0; off >>= 1) {
      float ov = __shfl_xor(bv, off, 64);
      int   om = __shfl_xor(bm, off, 64);
      if (ov > bv || (ov == bv && om < bm)) { bv = ov; bm = om; }
    }
    if (l == it) mine = bm;
    int wj = bm >> 6, wl = bm & 63;
    #pragma unroll
    for (int j = 0; j < 32; ++j)
      v[j] = (j == wj && l == wl) ? -3.4e38f : v[j];
  }
  if (l < K_) idxo[((size_t)b*N_ + n)*K_ + l] = mine;
}

// grid (N*K/128, B), block 256: K- and V-branch norm stats (gathered bundle).
__global__ __launch_bounds__(256) void kvstats_kernel(float* __restrict__ ws,
                                                      const int* __restrict__ idxp) {
  int t = threadIdx.x, o = t & 63, eg = t >> 6;
  int e0 = blockIdx.x * 128, b = blockIdx.y;
  const float* GB = ws + OFF_GB;
  const float* wK = ws + OFF_WK; const float* wV = ws + OFF_WV;
  int bN = b * N_;
  float k1 = 0.f, k2 = 0.f, v1 = 0.f, v2 = 0.f;
  for (int j = 0; j < 32; ++j) {
    int e = e0 + eg + j*4;
    int n = e >> 4, kk = e & 15;
    int m = idxp[(bN + n)*K_ + kk];
    int rb = (bN + n)*D3 + o*3;
    size_t gb = (size_t)(bN + m)*768 + o*3;      // bundle: seg0=uK, seg2=uV
    float p0 = GB[gb] + wK[rb], p1 = GB[gb+1] + wK[rb+1], p2 = GB[gb+2] + wK[rb+2];
    float nk = __builtin_amdgcn_sqrtf(p0*p0 + p1*p1 + p2*p2) + EPS_;
    k1 += nk; k2 += nk*nk;
    float q0 = GB[gb+384] + wV[rb], q1 = GB[gb+385] + wV[rb+1], q2 = GB[gb+386] + wV[rb+2];
    float nv = __builtin_amdgcn_sqrtf(q0*q0 + q1*q1 + q2*q2) + EPS_;
    v1 += nv; v2 += nv*nv;
  }
  __shared__ float red[4][256];
  red[0][t] = k1; red[1][t] = k2; red[2][t] = v1; red[3][t] = v2;
  __syncthreads();
  if (t < 64) {
    float* st = ws + OFF_ST;
    float a = red[0][t] + red[0][t+64] + red[0][t+128] + red[0][t+192];
    atomicAdd(&st[128 + t], a);
    a = red[1][t] + red[1][t+64] + red[1][t+128] + red[1][t+192];
    atomicAdd(&st[192 + t], a);
    a = red[2][t] + red[2][t+64] + red[2][t+128] + red[2][t+192];
    atomicAdd(&st[256 + t], a);
    a = red[3][t] + red[3][t+64] + red[3][t+128] + red[3][t+192];
    atomicAdd(&st[320 + t], a);
  }
}

// grid (N/4, B), block 256: wave w owns point n = bx*4+w, lane = channel o.
// BN fold inline (from raw sums). Pass A: K branch over 16 neighbors -> qk;
// softmax in regs; Pass B: V branch, weighted accumulate; float4 epilogue.
__global__ __launch_bounds__(256, 2) void final_kernel(const float* __restrict__ x,
                                                       const float* __restrict__ ws_c,
                                                       const int* __restrict__ idxp,
                                                       const float* __restrict__ gq,
                                                       const float* __restrict__ bq,
                                                       const float* __restrict__ gk,
                                                       const float* __restrict__ bk,
                                                       const float* __restrict__ gv,
                                                       const float* __restrict__ bv,
                                                       float* __restrict__ out) {
  const float* pq  = ws_c + OFF_PQ;  const float* dq  = ws_c + OFF_DQ;
  const float* GB  = ws_c + OFF_GB;
  const float* wK  = ws_c + OFF_WK;  const float* wDk = ws_c + OFF_WDK;
  const float* wV  = ws_c + OFF_WV;  const float* wDv = ws_c + OFF_WDV;
  const float* st  = ws_c + OFF_ST;
  int t = threadIdx.x, o = t & 63, w = t >> 6;
  int n0 = blockIdx.x*4, n = n0 + w, b = blockIdx.y;
  int bN = b * N_;
  __shared__ float ob2[192][5];           // [c*3+v][n-slot], stride 5
  // fold BN scale/shift from raw sums (redundant per wave; ~30 VALU)
  float sQ, shQ, sK, shK, sV, shV;
  {
    const float icq = 1.f / (float)(B_ * N_);
    float mu = st[o] * icq;
    float var = fmaxf(st[64+o]*icq - mu*mu, 0.f);
    sQ = gq[o] * rsqrtf(var + BNE_); shQ = bq[o] - mu*sQ;
    const float ick = 1.f / (float)(B_ * N_ * K_);
    mu = st[128+o] * ick;
    var = fmaxf(st[192+o]*ick - mu*mu, 0.f);
    sK = gk[o] * rsqrtf(var + BNE_); shK = bk[o] - mu*sK;
    mu = st[256+o] * ick;
    var = fmaxf(st[320+o]*ick - mu*mu, 0.f);
    sV = gv[o] * rsqrtf(var + BNE_); shV = bv[o] - mu*sV;
  }
  // neighbor indices (wave-uniform -> broadcast loads)
  int mi[16];
  {
    const int* ip = idxp + (size_t)(bN + n)*K_;
    int4 a0 = *(const int4*)&ip[0];  mi[0]=a0.x;  mi[1]=a0.y;  mi[2]=a0.z;  mi[3]=a0.w;
    int4 a1 = *(const int4*)&ip[4];  mi[4]=a1.x;  mi[5]=a1.y;  mi[6]=a1.z;  mi[7]=a1.w;
    int4 a2 = *(const int4*)&ip[8];  mi[8]=a2.x;  mi[9]=a2.y;  mi[10]=a2.z; mi[11]=a2.w;
    int4 a3 = *(const int4*)&ip[12]; mi[12]=a3.x; mi[13]=a3.y; mi[14]=a3.z; mi[15]=a3.w;
  }
  int rb = (bN + n)*D3 + o*3;
  // Q branch (once per n)
  float q0 = pq[rb], q1 = pq[rb+1], q2 = pq[rb+2];
  float e0 = dq[rb], e1 = dq[rb+1], e2 = dq[rb+2];
  vnlk(q0, q1, q2, e0, e1, e2, sQ, shQ);
  float qn2 = q0*q0 + q1*q1 + q2*q2;
  float qsc = chnorm_sc(__builtin_amdgcn_sqrtf(qn2),
                        __builtin_amdgcn_sqrtf(wred_sum(qn2)));
  float qx0 = q0*qsc, qx1 = q1*qsc, qx2 = q2*qsc;
  float wk0 = wK[rb],  wk1 = wK[rb+1],  wk2 = wK[rb+2];
  float wdk0= wDk[rb], wdk1= wDk[rb+1], wdk2= wDk[rb+2];
  const float isq = 0.07216878364870323f;   // 1/sqrt(3*C)
  // ---- pass A: K branch -> qk[16]  (bundle seg0=uK, seg1=uDk)
  float qk[16];
  #pragma unroll
  for (int kk = 0; kk < 16; ++kk) {
    size_t gb = (size_t)(bN + mi[kk])*768 + o*3;
    float p0 = GB[gb]     + wk0, p1 = GB[gb+1]   + wk1, p2 = GB[gb+2]   + wk2;
    float f0 = GB[gb+192] + wdk0, f1 = GB[gb+193] + wdk1, f2 = GB[gb+194] + wdk2;
    vnlk(p0, p1, p2, f0, f1, f2, sK, shK);
    float nc2 = p0*p0 + p1*p1 + p2*p2;
    float sc = chnorm_sc(__builtin_amdgcn_sqrtf(nc2),
                         __builtin_amdgcn_sqrtf(wred_sum(nc2)));
    qk[kk] = (p0*qx0 + p1*qx1 + p2*qx2) * (sc * isq);
  }
  // ---- softmax over 16 in registers
  float mx = qk[0];
  #pragma unroll
  for (int kk = 1; kk < 16; ++kk) mx = fmaxf(mx, qk[kk]);
  float se = 0.f;
  #pragma unroll
  for (int kk = 0; kk < 16; ++kk) { float e = __expf(qk[kk] - mx); qk[kk] = e; se += e; }
  float inv = __builtin_amdgcn_rcpf(se);
  // ---- pass B: V branch (bundle seg2=uV, seg3=uDv), weighted accumulate
  float wv0 = wV[rb],  wv1 = wV[rb+1],  wv2 = wV[rb+2];
  float wdv0= wDv[rb], wdv1= wDv[rb+1], wdv2= wDv[rb+2];
  float a0 = 0.f, a1 = 0.f, a2 = 0.f;
  #pragma unroll
  for (int kk = 0; kk < 16; ++kk) {
    size_t gb = (size_t)(bN + mi[kk])*768 + o*3;
    float v0 = GB[gb+384] + wv0, v1 = GB[gb+385] + wv1, v2 = GB[gb+386] + wv2;
    float g0 = GB[gb+576] + wdv0, g1 = GB[gb+577] + wdv1, g2 = GB[gb+578] + wdv2;
    vnlk(v0, v1, v2, g0, g1, g2, sV, shV);
    float at = qk[kk] * inv;
    a0 = fmaf(at, v0, a0); a1 = fmaf(at, v1, a1); a2 = fmaf(at, v2, a2);
  }
  ob2[o*3 + 0][w] = a0;
  ob2[o*3 + 1][w] = a1;
  ob2[o*3 + 2][w] = a2;
  __syncthreads();
  if (t < 192) {                          // t == c*3+v; 4 consecutive n per row
    size_t xo = ((size_t)b*D3 + t)*N_ + n0;
    float4 xr = *(const float4*)&x[xo];
    float4 r;
    r.x = xr.x + ob2[t][0]; r.y = xr.y + ob2[t][1];
    r.z = xr.z + ob2[t][2]; r.w = xr.w + ob2[t][3];
    *(float4*)&out[xo] = r;
  }
}

extern "C" void kernel_launch(void* const* d_in, const int* in_sizes, int n_in,
                              void* d_out, int out_size, void* d_ws, size_t ws_size,
                              hipStream_t stream) {
  const float* x  = (const float*)d_in[0];
  const float* y  = (const float*)d_in[1];
  const float* Wq = (const float*)d_in[2];
  const float* Dq = (const float*)d_in[3];
  const float* gq = (const float*)d_in[4];
  const float* bq = (const float*)d_in[5];
  const float* Wk = (const float*)d_in[6];
  const float* Dk = (const float*)d_in[7];
  const float* gk = (const float*)d_in[8];
  const float* bk = (const float*)d_in[9];
  const float* Wv = (const float*)d_in[10];
  const float* Dv = (const float*)d_in[11];
  const float* gv = (const float*)d_in[12];
  const float* bv = (const float*)d_in[13];
  float* ws = (float*)d_ws;
  float* out = (float*)d_out;
  int* idxp = (int*)(ws + OFF_IDX);

  // batched kNN if the workspace can hold B full NxN dist buffers (~130 MB)
  const size_t need = (OFF_DIST + (size_t)B_*N_*N_) * sizeof(float);
  const bool batched = ws_size >= need;

  hipMemsetAsync((void*)(ws + OFF_ST), 0, 1024 * sizeof(float), stream);
  transform_kernel<<<dim3(N_/32, B_, 6), 256, 0, stream>>>(x, y, Wq, Dq, Wk, Dk, Wv, Dv, ws);
  if (batched) {
    dist_kernel<<<dim3(N_/128, N_/64, B_), 256, 0, stream>>>(y, ws, 0, (size_t)N_*N_);
    topk_kernel<<<dim3(N_/4, B_), 256, 0, stream>>>(ws, idxp, 0, (size_t)N_*N_);
  } else {
    for (int b = 0; b < B_; ++b) {
      dist_kernel<<<dim3(N_/128, N_/64, 1), 256, 0, stream>>>(y, ws, b, 0);
      topk_kernel<<<dim3(N_/4, 1), 256, 0, stream>>>(ws, idxp, b, 0);
    }
  }
  kvstats_kernel<<<dim3(N_*K_/128, B_), 256, 0, stream>>>(ws, idxp);
  final_kernel<<<dim3(N_/4, B_), 256, 0, stream>>>(x, ws, idxp, gq, bq, gk, bk, gv, bv, out);
}

// Round 7
// 343.649 us; speedup vs baseline: 1.0985x; 1.0402x over previous
//
#include <hip/hip_runtime.h>
#include <cstdint>
#include <cstddef>

// CrossContext: VN attention block. B=4, C=64, N=2048, K=16, fp32.
constexpr int B_ = 4, C_ = 64, N_ = 2048, K_ = 16;
constexpr int D3 = 192;                    // 3*C
constexpr float EPS_ = 1e-6f, BNE_ = 1e-5f, NEG_ = 0.2f;
constexpr size_t S_ = (size_t)B_ * N_ * D3;   // 1,572,864 floats per tensor

// workspace float offsets
// GB bundle: [b][n][4][192] segs {uK,uDk,uV,uDv} -> 3KB contiguous per point
constexpr size_t OFF_PQ  = 0;        // Wq·x   [b][n][192]
constexpr size_t OFF_DQ  = 1*S_;     // Dq·x
constexpr size_t OFF_GB  = 2*S_;     // bundle (4*S_)
constexpr size_t OFF_WK  = 6*S_;     // (Wk2-Wk1)·y  (center parts, [b][n][192])
constexpr size_t OFF_WDK = 7*S_;
constexpr size_t OFF_WV  = 8*S_;
constexpr size_t OFF_WDV = 9*S_;
constexpr size_t OFF_SQ  = 10*S_;                       // B*N
constexpr size_t OFF_ST  = OFF_SQ + (size_t)B_*N_;      // 1024 floats stats
constexpr size_t OFF_IDX = OFF_ST + 1024;               // B*N*K ints
constexpr size_t OFF_DIST= OFF_IDX + (size_t)B_*N_*K_;  // N*N (x4 if ws allows)

__device__ __forceinline__ float wred_sum(float v) {
  #pragma unroll
  for (int off = 32; off > 0; off >>= 1) v += __shfl_xor(v, off, 64);
  return v;
}

// async global->LDS, 16B per lane. LDS dest must be linear: base + lane*16.
__device__ __forceinline__ void gld_lds16(const float* g, float* l) {
  __builtin_amdgcn_global_load_lds(
      (const __attribute__((address_space(1))) void*)g,
      (__attribute__((address_space(3))) void*)l, 16, 0, 0);
}

// VN BatchNorm(folded scale/shift) + LeakyReLU on one 3-vector. Branchless,
// native rcp/sqrt (1 ulp; output headroom 0.0156 vs 0.109 threshold).
__device__ __forceinline__ void vnlk(float& p0, float& p1, float& p2,
                                     float d0, float d1, float d2,
                                     float s, float sh) {
  float n2 = p0*p0 + p1*p1 + p2*p2;
  float norm = __builtin_amdgcn_sqrtf(n2) + EPS_;
  float f = fmaf(norm, s, sh) * __builtin_amdgcn_rcpf(norm);   // norm_bn/norm
  p0 *= f; p1 *= f; p2 *= f;
  float dot = p0*d0 + p1*d1 + p2*d2;
  float dns = d0*d0 + d1*d1 + d2*d2;
  float g = (1.f - NEG_) * fminf(dot, 0.f) * __builtin_amdgcn_rcpf(dns + EPS_);
  p0 = fmaf(-g, d0, p0); p1 = fmaf(-g, d1, p1); p2 = fmaf(-g, d2, p2);
}

// chnorm scale: p * sc, sc = n/(max(n,1e-12)*max(nch,1e-12))
__device__ __forceinline__ float chnorm_sc(float nc, float nch) {
  return nc * __builtin_amdgcn_rcpf(fmaxf(nc, 1e-12f))
            * __builtin_amdgcn_rcpf(fmaxf(nch, 1e-12f));
}

// ---------------- transforms: out[b][n][o*3+v] = sum_c W[o][c] in[b][c][v][n] --
// rs0: row stride (in floats) of out0 (768 for bundle segs, 192 otherwise).
template<bool PAIR>
__device__ __forceinline__ void do_mm(const float (*ys)[36], const float (*Wl)[129],
                                      float* __restrict__ out0, float* __restrict__ out1,
                                      float* s1s, float* s2s, bool qs,
                                      int og, int ng, int b, int n0, int rs0) {
  float accU[4][2][3] = {};
  float accW[4][2][3] = {};
  #pragma unroll 4
  for (int c = 0; c < 64; ++c) {
    float w1[4], wd[4];
    #pragma unroll
    for (int i = 0; i < 4; ++i) {
      w1[i] = Wl[og*4 + i][c];
      if (PAIR) wd[i] = Wl[og*4 + i][64 + c] - w1[i];
    }
    #pragma unroll
    for (int jj = 0; jj < 2; ++jj)
      #pragma unroll
      for (int v = 0; v < 3; ++v) {
        float yv = ys[c*3 + v][ng*2 + jj];
        #pragma unroll
        for (int i = 0; i < 4; ++i) {
          accU[i][jj][v] = fmaf(w1[i], yv, accU[i][jj][v]);
          if (PAIR) accW[i][jj][v] = fmaf(wd[i], yv, accW[i][jj][v]);
        }
      }
  }
  #pragma unroll
  for (int jj = 0; jj < 2; ++jj) {
    int n = n0 + ng*2 + jj;
    size_t base0 = ((size_t)b*N_ + n)*rs0 + og*12;
    alignas(16) float tmp[12];
    #pragma unroll
    for (int i = 0; i < 4; ++i)
      #pragma unroll
      for (int v = 0; v < 3; ++v) tmp[i*3+v] = accU[i][jj][v];
    float4* dst = (float4*)(out0 + base0);
    dst[0] = ((float4*)tmp)[0]; dst[1] = ((float4*)tmp)[1]; dst[2] = ((float4*)tmp)[2];
    if (PAIR) {
      size_t base1 = ((size_t)b*N_ + n)*D3 + og*12;
      #pragma unroll
      for (int i = 0; i < 4; ++i)
        #pragma unroll
        for (int v = 0; v < 3; ++v) tmp[i*3+v] = accW[i][jj][v];
      float4* dst1 = (float4*)(out1 + base1);
      dst1[0] = ((float4*)tmp)[0]; dst1[1] = ((float4*)tmp)[1]; dst1[2] = ((float4*)tmp)[2];
    }
  }
  if (!PAIR && qs) {    // fold Q-branch BN stats in (pre-BN norms of p)
    #pragma unroll
    for (int i = 0; i < 4; ++i) {
      float a = 0.f, b2 = 0.f;
      #pragma unroll
      for (int jj = 0; jj < 2; ++jj) {
        float nn = sqrtf(accU[i][jj][0]*accU[i][jj][0] + accU[i][jj][1]*accU[i][jj][1]
                       + accU[i][jj][2]*accU[i][jj][2]) + EPS_;
        a += nn; b2 += nn*nn;
      }
      atomicAdd(&s1s[og*4 + i], a);
      atomicAdd(&s2s[og*4 + i], b2);
    }
  }
}

// grid (N/32, B, 6): z in {Wq·x, Dq·x, Wk·y, Dk·y, Wv·y, Dv·y}
__global__ __launch_bounds__(256) void transform_kernel(
    const float* __restrict__ x, const float* __restrict__ y,
    const float* __restrict__ Wq, const float* __restrict__ Dq,
    const float* __restrict__ Wk, const float* __restrict__ Dk,
    const float* __restrict__ Wv, const float* __restrict__ Dv,
    float* __restrict__ ws) {
  __shared__ float ys[D3][36];
  __shared__ float Wl[64][129];
  __shared__ float s1s[64], s2s[64];
  int t = threadIdx.x, n0 = blockIdx.x*32, b = blockIdx.y, z = blockIdx.z;
  const bool isx = (z < 2);
  const float* in = (isx ? x : y) + (size_t)b*D3*N_;
  #pragma unroll
  for (int i = 0; i < 6; ++i) {           // 192*32/4/256
    int lin = t + i*256;
    int d = lin >> 3, c4 = (lin & 7)*4;
    *(float4*)&ys[d][c4] = *(const float4*)&in[(size_t)d*N_ + n0 + c4];
  }
  const float* Wg = (z==0)?Wq:(z==1)?Dq:(z==2)?Wk:(z==3)?Dk:(z==4)?Wv:Dv;
  if (isx) { for (int i = t; i < 4096; i += 256) Wl[i>>6][i&63] = Wg[i]; }
  else     { for (int i = t; i < 8192; i += 256) Wl[i>>7][i&127] = Wg[i]; }
  if (z == 0 && t < 64) { s1s[t] = 0.f; s2s[t] = 0.f; }
  __syncthreads();
  if (z == 2 && t < 32) {                 // sq for kNN (d ascending, matches ref)
    float s = 0.f;
    for (int d = 0; d < D3; ++d) { float v = ys[d][t]; s += v*v; }
    ws[OFF_SQ + (size_t)b*N_ + n0 + t] = s;
  }
  int og = t & 15, ng = t >> 4;
  float* st = ws + OFF_ST;
  if (isx) {
    float* out0 = ws + (z ? OFF_DQ : OFF_PQ);
    do_mm<false>(ys, Wl, out0, nullptr, s1s, s2s, z == 0, og, ng, b, n0, D3);
    if (z == 0) {
      __syncthreads();
      if (t < 64) { atomicAdd(&st[t], s1s[t]); atomicAdd(&st[64 + t], s2s[t]); }
    }
  } else {
    int seg = z - 2;                      // 0..3: uK,uDk,uV,uDv
    float* out0 = ws + OFF_GB + (size_t)seg*192;
    float* out1 = ws + ((z==2)?OFF_WK:(z==3)?OFF_WDK:(z==4)?OFF_WV:OFF_WDV);
    do_mm<true>(ys, Wl, out0, out1, nullptr, nullptr, false, og, ng, b, n0, 768);
  }
}

// ---------------- kNN dist: 128n x 128m tile, async LDS double-buffer ---------
// grid (N/128, N/128, nb), block 256, 8x8 acc/thread (split halves so all LDS
// reads are <=2-way bank-aliased = free). dist[n][m] = 2*dot - sq[n] - sq[m].
// FP accumulation order (dd ascending 0..191) identical to all passing rounds.
__global__ __launch_bounds__(256) void dist_kernel(const float* __restrict__ y,
                                                   float* __restrict__ ws,
                                                   int b0, size_t dstride) {
  __shared__ float As[2][4096];           // [32][128] linear (gload_lds needs linear)
  __shared__ float Bs[2][4096];           // [32][128] linear
  int b = b0 + blockIdx.z;
  const float* yb = y + (size_t)b * D3 * N_;      // [192][N]
  const float* sq = ws + OFF_SQ + (size_t)b * N_;
  float* dist = ws + OFF_DIST + dstride * blockIdx.z;
  int t = threadIdx.x;
  int m0 = blockIdx.x * 128, n0 = blockIdx.y * 128;
  int tm = t & 15, tn = t >> 4;           // 16 m-groups x 16 n-groups

  auto stage = [&](int buf, int dt) {
    #pragma unroll
    for (int j = 0; j < 4; ++j) {         // As: 1024 float4
      int idx = j*256 + t;
      gld_lds16(&yb[(size_t)(dt*32 + (idx >> 5))*N_ + n0 + (idx & 31)*4],
                &As[buf][idx*4]);
    }
    #pragma unroll
    for (int j = 0; j < 4; ++j) {         // Bs: 1024 float4
      int idx = j*256 + t;
      gld_lds16(&yb[(size_t)(dt*32 + (idx >> 5))*N_ + m0 + (idx & 31)*4],
                &Bs[buf][idx*4]);
    }
  };

  float acc[8][8] = {};                   // n: {tn*4+j, 64+tn*4+j}, m likewise
  stage(0, 0);
  __syncthreads();                        // drain vmcnt -> buf0 ready
  int cur = 0;
  for (int dt = 0; dt < 6; ++dt) {
    if (dt < 5) stage(cur ^ 1, dt + 1);   // async: in flight during FMAs
    const float* Ac = As[cur];
    const float* Bc = Bs[cur];
    #pragma unroll 4
    for (int dd = 0; dd < 32; ++dd) {
      float4 a0 = *(const float4*)&Ac[dd*128 + tn*4];
      float4 a1 = *(const float4*)&Ac[dd*128 + 64 + tn*4];
      float4 b0 = *(const float4*)&Bc[dd*128 + tm*4];
      float4 b1 = *(const float4*)&Bc[dd*128 + 64 + tm*4];
      float an[8] = {a0.x, a0.y, a0.z, a0.w, a1.x, a1.y, a1.z, a1.w};
      float bm[8] = {b0.x, b0.y, b0.z, b0.w, b1.x, b1.y, b1.z, b1.w};
      #pragma unroll
      for (int j = 0; j < 8; ++j)
        #pragma unroll
        for (int i = 0; i < 8; ++i)
          acc[j][i] = fmaf(an[j], bm[i], acc[j][i]);
    }
    __syncthreads();                      // drains this iter's stage; swap safe
    cur ^= 1;
  }
  float4 s0 = *(const float4*)&sq[m0 + tm*4];
  float4 s1 = *(const float4*)&sq[m0 + 64 + tm*4];
  float smv[8] = {s0.x, s0.y, s0.z, s0.w, s1.x, s1.y, s1.z, s1.w};
  #pragma unroll
  for (int j = 0; j < 8; ++j) {
    int n = n0 + ((j < 4) ? (tn*4 + j) : (64 + tn*4 + j - 4));
    float sn = sq[n];
    float4 r0, r1;
    r0.x = 2.f*acc[j][0] - sn - smv[0]; r0.y = 2.f*acc[j][1] - sn - smv[1];
    r0.z = 2.f*acc[j][2] - sn - smv[2]; r0.w = 2.f*acc[j][3] - sn - smv[3];
    r1.x = 2.f*acc[j][4] - sn - smv[4]; r1.y = 2.f*acc[j][5] - sn - smv[5];
    r1.z = 2.f*acc[j][6] - sn - smv[6]; r1.w = 2.f*acc[j][7] - sn - smv[7];
    size_t rowb = (size_t)n*N_ + m0 + tm*4;
    *(float4*)&dist[rowb]      = r0;
    *(float4*)&dist[rowb + 64] = r1;
  }
}

// grid (N/4, nb), block 256: ONE WAVE PER ROW, no barriers. Each lane holds 32
// elements (m = j*64 + lane) in registers; 16x {local argmax, butterfly argmax
// with (value desc, m asc) order, predicated winner mask}. Matches jax top_k.
__global__ __launch_bounds__(256) void topk_kernel(const float* __restrict__ ws_c,
                                                   int* __restrict__ idxo,
                                                   int b0, size_t dstride) {
  int t = threadIdx.x;
  int w = t >> 6, l = t & 63;
  int n = blockIdx.x*4 + w;
  int b = b0 + blockIdx.y;
  const float* dr = ws_c + OFF_DIST + dstride*blockIdx.y + (size_t)n * N_;
  float v[32];
  #pragma unroll
  for (int j = 0; j < 32; ++j) v[j] = dr[j*64 + l];
  int mine = 0;
  for (int it = 0; it < K_; ++it) {
    float bv = v[0]; int bj = 0;
    #pragma unroll
    for (int j = 1; j < 32; ++j) {
      bool g = v[j] > bv;
      bv = g ? v[j] : bv;
      bj = g ? j : bj;
    }
    int bm = bj*64 + l;
    #pragma unroll
    for (int off = 32; off > 0; off >>= 1) {
      float ov = __shfl_xor(bv, off, 64);
      int   om = __shfl_xor(bm, off, 64);
      if (ov > bv || (ov == bv && om < bm)) { bv = ov; bm = om; }
    }
    if (l == it) mine = bm;
    int wj = bm >> 6, wl = bm & 63;
    #pragma unroll
    for (int j = 0; j < 32; ++j)
      v[j] = (j == wj && l == wl) ? -3.4e38f : v[j];
  }
  if (l < K_) idxo[((size_t)b*N_ + n)*K_ + l] = mine;
}

// grid (N*K/128, B), block 256: K- and V-branch norm stats (gathered bundle).
__global__ __launch_bounds__(256) void kvstats_kernel(float* __restrict__ ws,
                                                      const int* __restrict__ idxp) {
  int t = threadIdx.x, o = t & 63, eg = t >> 6;
  int e0 = blockIdx.x * 128, b = blockIdx.y;
  const float* GB = ws + OFF_GB;
  const float* wK = ws + OFF_WK; const float* wV = ws + OFF_WV;
  int bN = b * N_;
  float k1 = 0.f, k2 = 0.f, v1 = 0.f, v2 = 0.f;
  for (int j = 0; j < 32; ++j) {
    int e = e0 + eg + j*4;
    int n = e >> 4, kk = e & 15;
    int m = idxp[(bN + n)*K_ + kk];
    int rb = (bN + n)*D3 + o*3;
    size_t gb = (size_t)(bN + m)*768 + o*3;      // bundle: seg0=uK, seg2=uV
    float p0 = GB[gb] + wK[rb], p1 = GB[gb+1] + wK[rb+1], p2 = GB[gb+2] + wK[rb+2];
    float nk = __builtin_amdgcn_sqrtf(p0*p0 + p1*p1 + p2*p2) + EPS_;
    k1 += nk; k2 += nk*nk;
    float q0 = GB[gb+384] + wV[rb], q1 = GB[gb+385] + wV[rb+1], q2 = GB[gb+386] + wV[rb+2];
    float nv = __builtin_amdgcn_sqrtf(q0*q0 + q1*q1 + q2*q2) + EPS_;
    v1 += nv; v2 += nv*nv;
  }
  __shared__ float red[4][256];
  red[0][t] = k1; red[1][t] = k2; red[2][t] = v1; red[3][t] = v2;
  __syncthreads();
  if (t < 64) {
    float* st = ws + OFF_ST;
    float a = red[0][t] + red[0][t+64] + red[0][t+128] + red[0][t+192];
    atomicAdd(&st[128 + t], a);
    a = red[1][t] + red[1][t+64] + red[1][t+128] + red[1][t+192];
    atomicAdd(&st[192 + t], a);
    a = red[2][t] + red[2][t+64] + red[2][t+128] + red[2][t+192];
    atomicAdd(&st[256 + t], a);
    a = red[3][t] + red[3][t+64] + red[3][t+128] + red[3][t+192];
    atomicAdd(&st[320 + t], a);
  }
}

// grid (N/4, B), block 256: wave w owns point n = bx*4+w, lane = channel o.
// BN fold inline (from raw sums). Pass A: K branch over 16 neighbors -> qk;
// softmax in regs; Pass B: V branch, weighted accumulate; float4 epilogue.
__global__ __launch_bounds__(256, 2) void final_kernel(const float* __restrict__ x,
                                                       const float* __restrict__ ws_c,
                                                       const int* __restrict__ idxp,
                                                       const float* __restrict__ gq,
                                                       const float* __restrict__ bq,
                                                       const float* __restrict__ gk,
                                                       const float* __restrict__ bk,
                                                       const float* __restrict__ gv,
                                                       const float* __restrict__ bv,
                                                       float* __restrict__ out) {
  const float* pq  = ws_c + OFF_PQ;  const float* dq  = ws_c + OFF_DQ;
  const float* GB  = ws_c + OFF_GB;
  const float* wK  = ws_c + OFF_WK;  const float* wDk = ws_c + OFF_WDK;
  const float* wV  = ws_c + OFF_WV;  const float* wDv = ws_c + OFF_WDV;
  const float* st  = ws_c + OFF_ST;
  int t = threadIdx.x, o = t & 63, w = t >> 6;
  int n0 = blockIdx.x*4, n = n0 + w, b = blockIdx.y;
  int bN = b * N_;
  __shared__ float ob2[192][5];           // [c*3+v][n-slot], stride 5
  // fold BN scale/shift from raw sums (redundant per wave; ~30 VALU)
  float sQ, shQ, sK, shK, sV, shV;
  {
    const float icq = 1.f / (float)(B_ * N_);
    float mu = st[o] * icq;
    float var = fmaxf(st[64+o]*icq - mu*mu, 0.f);
    sQ = gq[o] * rsqrtf(var + BNE_); shQ = bq[o] - mu*sQ;
    const float ick = 1.f / (float)(B_ * N_ * K_);
    mu = st[128+o] * ick;
    var = fmaxf(st[192+o]*ick - mu*mu, 0.f);
    sK = gk[o] * rsqrtf(var + BNE_); shK = bk[o] - mu*sK;
    mu = st[256+o] * ick;
    var = fmaxf(st[320+o]*ick - mu*mu, 0.f);
    sV = gv[o] * rsqrtf(var + BNE_); shV = bv[o] - mu*sV;
  }
  // neighbor indices (wave-uniform -> broadcast loads)
  int mi[16];
  {
    const int* ip = idxp + (size_t)(bN + n)*K_;
    int4 a0 = *(const int4*)&ip[0];  mi[0]=a0.x;  mi[1]=a0.y;  mi[2]=a0.z;  mi[3]=a0.w;
    int4 a1 = *(const int4*)&ip[4];  mi[4]=a1.x;  mi[5]=a1.y;  mi[6]=a1.z;  mi[7]=a1.w;
    int4 a2 = *(const int4*)&ip[8];  mi[8]=a2.x;  mi[9]=a2.y;  mi[10]=a2.z; mi[11]=a2.w;
    int4 a3 = *(const int4*)&ip[12]; mi[12]=a3.x; mi[13]=a3.y; mi[14]=a3.z; mi[15]=a3.w;
  }
  int rb = (bN + n)*D3 + o*3;
  // Q branch (once per n)
  float q0 = pq[rb], q1 = pq[rb+1], q2 = pq[rb+2];
  float e0 = dq[rb], e1 = dq[rb+1], e2 = dq[rb+2];
  vnlk(q0, q1, q2, e0, e1, e2, sQ, shQ);
  float qn2 = q0*q0 + q1*q1 + q2*q2;
  float qsc = chnorm_sc(__builtin_amdgcn_sqrtf(qn2),
                        __builtin_amdgcn_sqrtf(wred_sum(qn2)));
  float qx0 = q0*qsc, qx1 = q1*qsc, qx2 = q2*qsc;
  float wk0 = wK[rb],  wk1 = wK[rb+1],  wk2 = wK[rb+2];
  float wdk0= wDk[rb], wdk1= wDk[rb+1], wdk2= wDk[rb+2];
  const float isq = 0.07216878364870323f;   // 1/sqrt(3*C)
  // ---- pass A: K branch -> qk[16]  (bundle seg0=uK, seg1=uDk)
  float qk[16];
  #pragma unroll
  for (int kk = 0; kk < 16; ++kk) {
    size_t gb = (size_t)(bN + mi[kk])*768 + o*3;
    float p0 = GB[gb]     + wk0, p1 = GB[gb+1]   + wk1, p2 = GB[gb+2]   + wk2;
    float f0 = GB[gb+192] + wdk0, f1 = GB[gb+193] + wdk1, f2 = GB[gb+194] + wdk2;
    vnlk(p0, p1, p2, f0, f1, f2, sK, shK);
    float nc2 = p0*p0 + p1*p1 + p2*p2;
    float sc = chnorm_sc(__builtin_amdgcn_sqrtf(nc2),
                         __builtin_amdgcn_sqrtf(wred_sum(nc2)));
    qk[kk] = (p0*qx0 + p1*qx1 + p2*qx2) * (sc * isq);
  }
  // ---- softmax over 16 in registers
  float mx = qk[0];
  #pragma unroll
  for (int kk = 1; kk < 16; ++kk) mx = fmaxf(mx, qk[kk]);
  float se = 0.f;
  #pragma unroll
  for (int kk = 0; kk < 16; ++kk) { float e = __expf(qk[kk] - mx); qk[kk] = e; se += e; }
  float inv = __builtin_amdgcn_rcpf(se);
  // ---- pass B: V branch (bundle seg2=uV, seg3=uDv), weighted accumulate
  float wv0 = wV[rb],  wv1 = wV[rb+1],  wv2 = wV[rb+2];
  float wdv0= wDv[rb], wdv1= wDv[rb+1], wdv2= wDv[rb+2];
  float a0 = 0.f, a1 = 0.f, a2 = 0.f;
  #pragma unroll
  for (int kk = 0; kk < 16; ++kk) {
    size_t gb = (size_t)(bN + mi[kk])*768 + o*3;
    float v0 = GB[gb+384] + wv0, v1 = GB[gb+385] + wv1, v2 = GB[gb+386] + wv2;
    float g0 = GB[gb+576] + wdv0, g1 = GB[gb+577] + wdv1, g2 = GB[gb+578] + wdv2;
    vnlk(v0, v1, v2, g0, g1, g2, sV, shV);
    float at = qk[kk] * inv;
    a0 = fmaf(at, v0, a0); a1 = fmaf(at, v1, a1); a2 = fmaf(at, v2, a2);
  }
  ob2[o*3 + 0][w] = a0;
  ob2[o*3 + 1][w] = a1;
  ob2[o*3 + 2][w] = a2;
  __syncthreads();
  if (t < 192) {                          // t == c*3+v; 4 consecutive n per row
    size_t xo = ((size_t)b*D3 + t)*N_ + n0;
    float4 xr = *(const float4*)&x[xo];
    float4 r;
    r.x = xr.x + ob2[t][0]; r.y = xr.y + ob2[t][1];
    r.z = xr.z + ob2[t][2]; r.w = xr.w + ob2[t][3];
    *(float4*)&out[xo] = r;
  }
}

extern "C" void kernel_launch(void* const* d_in, const int* in_sizes, int n_in,
                              void* d_out, int out_size, void* d_ws, size_t ws_size,
                              hipStream_t stream) {
  const float* x  = (const float*)d_in[0];
  const float* y  = (const float*)d_in[1];
  const float* Wq = (const float*)d_in[2];
  const float* Dq = (const float*)d_in[3];
  const float* gq = (const float*)d_in[4];
  const float* bq = (const float*)d_in[5];
  const float* Wk = (const float*)d_in[6];
  const float* Dk = (const float*)d_in[7];
  const float* gk = (const float*)d_in[8];
  const float* bk = (const float*)d_in[9];
  const float* Wv = (const float*)d_in[10];
  const float* Dv = (const float*)d_in[11];
  const float* gv = (const float*)d_in[12];
  const float* bv = (const float*)d_in[13];
  float* ws = (float*)d_ws;
  float* out = (float*)d_out;
  int* idxp = (int*)(ws + OFF_IDX);

  // batched kNN if the workspace can hold B full NxN dist buffers (~130 MB)
  const size_t need = (OFF_DIST + (size_t)B_*N_*N_) * sizeof(float);
  const bool batched = ws_size >= need;

  hipMemsetAsync((void*)(ws + OFF_ST), 0, 1024 * sizeof(float), stream);
  transform_kernel<<<dim3(N_/32, B_, 6), 256, 0, stream>>>(x, y, Wq, Dq, Wk, Dk, Wv, Dv, ws);
  if (batched) {
    dist_kernel<<<dim3(N_/128, N_/128, B_), 256, 0, stream>>>(y, ws, 0, (size_t)N_*N_);
    topk_kernel<<<dim3(N_/4, B_), 256, 0, stream>>>(ws, idxp, 0, (size_t)N_*N_);
  } else {
    for (int b = 0; b < B_; ++b) {
      dist_kernel<<<dim3(N_/128, N_/128, 1), 256, 0, stream>>>(y, ws, b, 0);
      topk_kernel<<<dim3(N_/4, 1), 256, 0, stream>>>(ws, idxp, b, 0);
    }
  }
  kvstats_kernel<<<dim3(N_*K_/128, B_), 256, 0, stream>>>(ws, idxp);
  final_kernel<<<dim3(N_/4, B_), 256, 0, stream>>>(x, ws, idxp, gq, bq, gk, bk, gv, bv, out);
}

// Round 8
// 341.547 us; speedup vs baseline: 1.1053x; 1.0062x over previous
//
#include <hip/hip_runtime.h>
#include <cstdint>
#include <cstddef>

// CrossContext: VN attention block. B=4, C=64, N=2048, K=16, fp32.
constexpr int B_ = 4, C_ = 64, N_ = 2048, K_ = 16;
constexpr int D3 = 192;                    // 3*C
constexpr float EPS_ = 1e-6f, BNE_ = 1e-5f, NEG_ = 0.2f;
constexpr size_t S_ = (size_t)B_ * N_ * D3;   // 1,572,864 floats per tensor

// workspace float offsets
// GB bundle: [b][n][4][192] segs {uK,uDk,uV,uDv} -> 3KB contiguous per point
constexpr size_t OFF_PQ  = 0;        // Wq·x   [b][n][192]
constexpr size_t OFF_DQ  = 1*S_;     // Dq·x
constexpr size_t OFF_GB  = 2*S_;     // bundle (4*S_)
constexpr size_t OFF_WK  = 6*S_;     // (Wk2-Wk1)·y  (center parts, [b][n][192])
constexpr size_t OFF_WDK = 7*S_;
constexpr size_t OFF_WV  = 8*S_;
constexpr size_t OFF_WDV = 9*S_;
constexpr size_t OFF_SQ  = 10*S_;                       // B*N
constexpr size_t OFF_ST  = OFF_SQ + (size_t)B_*N_;      // 1024 floats stats
constexpr size_t OFF_IDX = OFF_ST + 1024;               // B*N*K ints
constexpr size_t OFF_DIST= OFF_IDX + (size_t)B_*N_*K_;  // N*N (x4 if ws allows)

__device__ __forceinline__ float wred_sum(float v) {
  #pragma unroll
  for (int off = 32; off > 0; off >>= 1) v += __shfl_xor(v, off, 64);
  return v;
}

// async global->LDS, 16B per lane. LDS dest must be linear: base + lane*16.
__device__ __forceinline__ void gld_lds16(const float* g, float* l) {
  __builtin_amdgcn_global_load_lds(
      (const __attribute__((address_space(1))) void*)g,
      (__attribute__((address_space(3))) void*)l, 16, 0, 0);
}

// VN BatchNorm(folded scale/shift) + LeakyReLU on one 3-vector. Branchless,
// native rcp/sqrt (1 ulp; output headroom 0.0156 vs 0.109 threshold).
__device__ __forceinline__ void vnlk(float& p0, float& p1, float& p2,
                                     float d0, float d1, float d2,
                                     float s, float sh) {
  float n2 = p0*p0 + p1*p1 + p2*p2;
  float norm = __builtin_amdgcn_sqrtf(n2) + EPS_;
  float f = fmaf(norm, s, sh) * __builtin_amdgcn_rcpf(norm);   // norm_bn/norm
  p0 *= f; p1 *= f; p2 *= f;
  float dot = p0*d0 + p1*d1 + p2*d2;
  float dns = d0*d0 + d1*d1 + d2*d2;
  float g = (1.f - NEG_) * fminf(dot, 0.f) * __builtin_amdgcn_rcpf(dns + EPS_);
  p0 = fmaf(-g, d0, p0); p1 = fmaf(-g, d1, p1); p2 = fmaf(-g, d2, p2);
}

// chnorm scale: p * sc, sc = n/(max(n,1e-12)*max(nch,1e-12))
__device__ __forceinline__ float chnorm_sc(float nc, float nch) {
  return nc * __builtin_amdgcn_rcpf(fmaxf(nc, 1e-12f))
            * __builtin_amdgcn_rcpf(fmaxf(nch, 1e-12f));
}

// ---------------- transforms: out[b][n][o*3+v] = sum_c W[o][c] in[b][c][v][n] --
// rs0: row stride (in floats) of out0 (768 for bundle segs, 192 otherwise).
template<bool PAIR>
__device__ __forceinline__ void do_mm(const float (*ys)[36], const float (*Wl)[129],
                                      float* __restrict__ out0, float* __restrict__ out1,
                                      float* s1s, float* s2s, bool qs,
                                      int og, int ng, int b, int n0, int rs0) {
  float accU[4][2][3] = {};
  float accW[4][2][3] = {};
  #pragma unroll 4
  for (int c = 0; c < 64; ++c) {
    float w1[4], wd[4];
    #pragma unroll
    for (int i = 0; i < 4; ++i) {
      w1[i] = Wl[og*4 + i][c];
      if (PAIR) wd[i] = Wl[og*4 + i][64 + c] - w1[i];
    }
    #pragma unroll
    for (int jj = 0; jj < 2; ++jj)
      #pragma unroll
      for (int v = 0; v < 3; ++v) {
        float yv = ys[c*3 + v][ng*2 + jj];
        #pragma unroll
        for (int i = 0; i < 4; ++i) {
          accU[i][jj][v] = fmaf(w1[i], yv, accU[i][jj][v]);
          if (PAIR) accW[i][jj][v] = fmaf(wd[i], yv, accW[i][jj][v]);
        }
      }
  }
  #pragma unroll
  for (int jj = 0; jj < 2; ++jj) {
    int n = n0 + ng*2 + jj;
    size_t base0 = ((size_t)b*N_ + n)*rs0 + og*12;
    alignas(16) float tmp[12];
    #pragma unroll
    for (int i = 0; i < 4; ++i)
      #pragma unroll
      for (int v = 0; v < 3; ++v) tmp[i*3+v] = accU[i][jj][v];
    float4* dst = (float4*)(out0 + base0);
    dst[0] = ((float4*)tmp)[0]; dst[1] = ((float4*)tmp)[1]; dst[2] = ((float4*)tmp)[2];
    if (PAIR) {
      size_t base1 = ((size_t)b*N_ + n)*D3 + og*12;
      #pragma unroll
      for (int i = 0; i < 4; ++i)
        #pragma unroll
        for (int v = 0; v < 3; ++v) tmp[i*3+v] = accW[i][jj][v];
      float4* dst1 = (float4*)(out1 + base1);
      dst1[0] = ((float4*)tmp)[0]; dst1[1] = ((float4*)tmp)[1]; dst1[2] = ((float4*)tmp)[2];
    }
  }
  if (!PAIR && qs) {    // fold Q-branch BN stats in (pre-BN norms of p)
    #pragma unroll
    for (int i = 0; i < 4; ++i) {
      float a = 0.f, b2 = 0.f;
      #pragma unroll
      for (int jj = 0; jj < 2; ++jj) {
        float nn = sqrtf(accU[i][jj][0]*accU[i][jj][0] + accU[i][jj][1]*accU[i][jj][1]
                       + accU[i][jj][2]*accU[i][jj][2]) + EPS_;
        a += nn; b2 += nn*nn;
      }
      atomicAdd(&s1s[og*4 + i], a);
      atomicAdd(&s2s[og*4 + i], b2);
    }
  }
}

// grid (N/32, B, 6): z in {Wq·x, Dq·x, Wk·y, Dk·y, Wv·y, Dv·y}
__global__ __launch_bounds__(256) void transform_kernel(
    const float* __restrict__ x, const float* __restrict__ y,
    const float* __restrict__ Wq, const float* __restrict__ Dq,
    const float* __restrict__ Wk, const float* __restrict__ Dk,
    const float* __restrict__ Wv, const float* __restrict__ Dv,
    float* __restrict__ ws) {
  __shared__ float ys[D3][36];
  __shared__ float Wl[64][129];
  __shared__ float s1s[64], s2s[64];
  int t = threadIdx.x, n0 = blockIdx.x*32, b = blockIdx.y, z = blockIdx.z;
  const bool isx = (z < 2);
  const float* in = (isx ? x : y) + (size_t)b*D3*N_;
  #pragma unroll
  for (int i = 0; i < 6; ++i) {           // 192*32/4/256
    int lin = t + i*256;
    int d = lin >> 3, c4 = (lin & 7)*4;
    *(float4*)&ys[d][c4] = *(const float4*)&in[(size_t)d*N_ + n0 + c4];
  }
  const float* Wg = (z==0)?Wq:(z==1)?Dq:(z==2)?Wk:(z==3)?Dk:(z==4)?Wv:Dv;
  if (isx) { for (int i = t; i < 4096; i += 256) Wl[i>>6][i&63] = Wg[i]; }
  else     { for (int i = t; i < 8192; i += 256) Wl[i>>7][i&127] = Wg[i]; }
  if (z == 0 && t < 64) { s1s[t] = 0.f; s2s[t] = 0.f; }
  __syncthreads();
  if (z == 2 && t < 32) {                 // sq for kNN (d ascending, matches ref)
    float s = 0.f;
    for (int d = 0; d < D3; ++d) { float v = ys[d][t]; s += v*v; }
    ws[OFF_SQ + (size_t)b*N_ + n0 + t] = s;
  }
  int og = t & 15, ng = t >> 4;
  float* st = ws + OFF_ST;
  if (isx) {
    float* out0 = ws + (z ? OFF_DQ : OFF_PQ);
    do_mm<false>(ys, Wl, out0, nullptr, s1s, s2s, z == 0, og, ng, b, n0, D3);
    if (z == 0) {
      __syncthreads();
      if (t < 64) { atomicAdd(&st[t], s1s[t]); atomicAdd(&st[64 + t], s2s[t]); }
    }
  } else {
    int seg = z - 2;                      // 0..3: uK,uDk,uV,uDv
    float* out0 = ws + OFF_GB + (size_t)seg*192;
    float* out1 = ws + ((z==2)?OFF_WK:(z==3)?OFF_WDK:(z==4)?OFF_WV:OFF_WDV);
    do_mm<true>(ys, Wl, out0, out1, nullptr, nullptr, false, og, ng, b, n0, 768);
  }
}

// ---------------- kNN dist: 128n x 256m tile, 8x16 acc/thread -----------------
// grid (N/256, N/128, nb), block 256, K-step dd=16, async LDS double-buffer
// (48 KB). Per dd: 6 ds_read_b128 (96B) -> 128 FMA (intensity 1.33 FMA/B, LDS
// stream now under the VALU shadow). All LDS reads: 16 unique addrs x 4-lane
// broadcast (<=2-way = free). dist[n][m] = 2*dot - sq[n] - sq[m].
// FP accumulation order (dd ascending 0..191) identical to all passing rounds.
__global__ __launch_bounds__(256) void dist_kernel(const float* __restrict__ y,
                                                   float* __restrict__ ws,
                                                   int b0, size_t dstride) {
  __shared__ float As[2][2048];           // [16][128] linear (gload_lds needs linear)
  __shared__ float Bs[2][4096];           // [16][256] linear
  int b = b0 + blockIdx.z;
  const float* yb = y + (size_t)b * D3 * N_;      // [192][N]
  const float* sq = ws + OFF_SQ + (size_t)b * N_;
  float* dist = ws + OFF_DIST + dstride * blockIdx.z;
  int t = threadIdx.x;
  int m0 = blockIdx.x * 256, n0 = blockIdx.y * 128;
  int tm = t & 15, tn = t >> 4;           // 16 m-groups x 16 n-groups

  auto stage = [&](int buf, int dt) {
    #pragma unroll
    for (int j = 0; j < 2; ++j) {         // As: 16x128 = 512 float4
      int idx = j*256 + t;
      gld_lds16(&yb[(size_t)(dt*16 + (idx >> 5))*N_ + n0 + (idx & 31)*4],
                &As[buf][idx*4]);
    }
    #pragma unroll
    for (int j = 0; j < 4; ++j) {         // Bs: 16x256 = 1024 float4
      int idx = j*256 + t;
      gld_lds16(&yb[(size_t)(dt*16 + (idx >> 6))*N_ + m0 + (idx & 63)*4],
                &Bs[buf][idx*4]);
    }
  };

  float acc[8][16] = {};                  // n: {tn*4+j, 64+tn*4+j}; m: 4 regions
  stage(0, 0);
  __syncthreads();                        // drain vmcnt -> buf0 ready
  int cur = 0;
  for (int dt = 0; dt < 12; ++dt) {
    if (dt < 11) stage(cur ^ 1, dt + 1);  // async: in flight during FMAs
    const float* Ac = As[cur];
    const float* Bc = Bs[cur];
    #pragma unroll 4
    for (int dd = 0; dd < 16; ++dd) {
      float4 a0 = *(const float4*)&Ac[dd*128 + tn*4];
      float4 a1 = *(const float4*)&Ac[dd*128 + 64 + tn*4];
      float4 b0 = *(const float4*)&Bc[dd*256 + tm*4];
      float4 b1 = *(const float4*)&Bc[dd*256 + 64 + tm*4];
      float4 b2 = *(const float4*)&Bc[dd*256 + 128 + tm*4];
      float4 b3 = *(const float4*)&Bc[dd*256 + 192 + tm*4];
      float an[8] = {a0.x, a0.y, a0.z, a0.w, a1.x, a1.y, a1.z, a1.w};
      float bm[16] = {b0.x, b0.y, b0.z, b0.w, b1.x, b1.y, b1.z, b1.w,
                      b2.x, b2.y, b2.z, b2.w, b3.x, b3.y, b3.z, b3.w};
      #pragma unroll
      for (int j = 0; j < 8; ++j)
        #pragma unroll
        for (int i = 0; i < 16; ++i)
          acc[j][i] = fmaf(an[j], bm[i], acc[j][i]);
    }
    __syncthreads();                      // drains this iter's stage; swap safe
    cur ^= 1;
  }
  float smv[16];
  #pragma unroll
  for (int r = 0; r < 4; ++r) {
    float4 s4 = *(const float4*)&sq[m0 + r*64 + tm*4];
    smv[r*4+0] = s4.x; smv[r*4+1] = s4.y; smv[r*4+2] = s4.z; smv[r*4+3] = s4.w;
  }
  #pragma unroll
  for (int j = 0; j < 8; ++j) {
    int n = n0 + ((j < 4) ? (tn*4 + j) : (64 + tn*4 + j - 4));
    float sn = sq[n];
    size_t rowb = (size_t)n*N_ + m0 + tm*4;
    #pragma unroll
    for (int r = 0; r < 4; ++r) {
      float4 rr;
      rr.x = 2.f*acc[j][r*4+0] - sn - smv[r*4+0];
      rr.y = 2.f*acc[j][r*4+1] - sn - smv[r*4+1];
      rr.z = 2.f*acc[j][r*4+2] - sn - smv[r*4+2];
      rr.w = 2.f*acc[j][r*4+3] - sn - smv[r*4+3];
      *(float4*)&dist[rowb + r*64] = rr;
    }
  }
}

// grid (N/4, nb), block 256: ONE WAVE PER ROW, no barriers. Each lane holds 32
// elements (m = j*64 + lane) in registers; 16x {local argmax, butterfly argmax
// with (value desc, m asc) order, predicated winner mask}. Matches jax top_k.
__global__ __launch_bounds__(256) void topk_kernel(const float* __restrict__ ws_c,
                                                   int* __restrict__ idxo,
                                                   int b0, size_t dstride) {
  int t = threadIdx.x;
  int w = t >> 6, l = t & 63;
  int n = blockIdx.x*4 + w;
  int b = b0 + blockIdx.y;
  const float* dr = ws_c + OFF_DIST + dstride*blockIdx.y + (size_t)n * N_;
  float v[32];
  #pragma unroll
  for (int j = 0; j < 32; ++j) v[j] = dr[j*64 + l];
  int mine = 0;
  for (int it = 0; it < K_; ++it) {
    float bv = v[0]; int bj = 0;
    #pragma unroll
    for (int j = 1; j < 32; ++j) {
      bool g = v[j] > bv;
      bv = g ? v[j] : bv;
      bj = g ? j : bj;
    }
    int bm = bj*64 + l;
    #pragma unroll
    for (int off = 32; off > 0; off >>= 1) {
      float ov = __shfl_xor(bv, off, 64);
      int   om = __shfl_xor(bm, off, 64);
      if (ov > bv || (ov == bv && om < bm)) { bv = ov; bm = om; }
    }
    if (l == it) mine = bm;
    int wj = bm >> 6, wl = bm & 63;
    #pragma unroll
    for (int j = 0; j < 32; ++j)
      v[j] = (j == wj && l == wl) ? -3.4e38f : v[j];
  }
  if (l < K_) idxo[((size_t)b*N_ + n)*K_ + l] = mine;
}

// grid (N*K/128, B), block 256: K- and V-branch norm stats (gathered bundle).
__global__ __launch_bounds__(256) void kvstats_kernel(float* __restrict__ ws,
                                                      const int* __restrict__ idxp) {
  int t = threadIdx.x, o = t & 63, eg = t >> 6;
  int e0 = blockIdx.x * 128, b = blockIdx.y;
  const float* GB = ws + OFF_GB;
  const float* wK = ws + OFF_WK; const float* wV = ws + OFF_WV;
  int bN = b * N_;
  float k1 = 0.f, k2 = 0.f, v1 = 0.f, v2 = 0.f;
  for (int j = 0; j < 32; ++j) {
    int e = e0 + eg + j*4;
    int n = e >> 4, kk = e & 15;
    int m = idxp[(bN + n)*K_ + kk];
    int rb = (bN + n)*D3 + o*3;
    size_t gb = (size_t)(bN + m)*768 + o*3;      // bundle: seg0=uK, seg2=uV
    float p0 = GB[gb] + wK[rb], p1 = GB[gb+1] + wK[rb+1], p2 = GB[gb+2] + wK[rb+2];
    float nk = __builtin_amdgcn_sqrtf(p0*p0 + p1*p1 + p2*p2) + EPS_;
    k1 += nk; k2 += nk*nk;
    float q0 = GB[gb+384] + wV[rb], q1 = GB[gb+385] + wV[rb+1], q2 = GB[gb+386] + wV[rb+2];
    float nv = __builtin_amdgcn_sqrtf(q0*q0 + q1*q1 + q2*q2) + EPS_;
    v1 += nv; v2 += nv*nv;
  }
  __shared__ float red[4][256];
  red[0][t] = k1; red[1][t] = k2; red[2][t] = v1; red[3][t] = v2;
  __syncthreads();
  if (t < 64) {
    float* st = ws + OFF_ST;
    float a = red[0][t] + red[0][t+64] + red[0][t+128] + red[0][t+192];
    atomicAdd(&st[128 + t], a);
    a = red[1][t] + red[1][t+64] + red[1][t+128] + red[1][t+192];
    atomicAdd(&st[192 + t], a);
    a = red[2][t] + red[2][t+64] + red[2][t+128] + red[2][t+192];
    atomicAdd(&st[256 + t], a);
    a = red[3][t] + red[3][t+64] + red[3][t+128] + red[3][t+192];
    atomicAdd(&st[320 + t], a);
  }
}

// grid (N/4, B), block 256: wave w owns point n = bx*4+w, lane = channel o.
// BN fold inline (from raw sums). Pass A: K branch over 16 neighbors -> qk;
// softmax in regs; Pass B: V branch, weighted accumulate; float4 epilogue.
__global__ __launch_bounds__(256, 2) void final_kernel(const float* __restrict__ x,
                                                       const float* __restrict__ ws_c,
                                                       const int* __restrict__ idxp,
                                                       const float* __restrict__ gq,
                                                       const float* __restrict__ bq,
                                                       const float* __restrict__ gk,
                                                       const float* __restrict__ bk,
                                                       const float* __restrict__ gv,
                                                       const float* __restrict__ bv,
                                                       float* __restrict__ out) {
  const float* pq  = ws_c + OFF_PQ;  const float* dq  = ws_c + OFF_DQ;
  const float* GB  = ws_c + OFF_GB;
  const float* wK  = ws_c + OFF_WK;  const float* wDk = ws_c + OFF_WDK;
  const float* wV  = ws_c + OFF_WV;  const float* wDv = ws_c + OFF_WDV;
  const float* st  = ws_c + OFF_ST;
  int t = threadIdx.x, o = t & 63, w = t >> 6;
  int n0 = blockIdx.x*4, n = n0 + w, b = blockIdx.y;
  int bN = b * N_;
  __shared__ float ob2[192][5];           // [c*3+v][n-slot], stride 5
  // fold BN scale/shift from raw sums (redundant per wave; ~30 VALU)
  float sQ, shQ, sK, shK, sV, shV;
  {
    const float icq = 1.f / (float)(B_ * N_);
    float mu = st[o] * icq;
    float var = fmaxf(st[64+o]*icq - mu*mu, 0.f);
    sQ = gq[o] * rsqrtf(var + BNE_); shQ = bq[o] - mu*sQ;
    const float ick = 1.f / (float)(B_ * N_ * K_);
    mu = st[128+o] * ick;
    var = fmaxf(st[192+o]*ick - mu*mu, 0.f);
    sK = gk[o] * rsqrtf(var + BNE_); shK = bk[o] - mu*sK;
    mu = st[256+o] * ick;
    var = fmaxf(st[320+o]*ick - mu*mu, 0.f);
    sV = gv[o] * rsqrtf(var + BNE_); shV = bv[o] - mu*sV;
  }
  // neighbor indices (wave-uniform -> broadcast loads)
  int mi[16];
  {
    const int* ip = idxp + (size_t)(bN + n)*K_;
    int4 a0 = *(const int4*)&ip[0];  mi[0]=a0.x;  mi[1]=a0.y;  mi[2]=a0.z;  mi[3]=a0.w;
    int4 a1 = *(const int4*)&ip[4];  mi[4]=a1.x;  mi[5]=a1.y;  mi[6]=a1.z;  mi[7]=a1.w;
    int4 a2 = *(const int4*)&ip[8];  mi[8]=a2.x;  mi[9]=a2.y;  mi[10]=a2.z; mi[11]=a2.w;
    int4 a3 = *(const int4*)&ip[12]; mi[12]=a3.x; mi[13]=a3.y; mi[14]=a3.z; mi[15]=a3.w;
  }
  int rb = (bN + n)*D3 + o*3;
  // Q branch (once per n)
  float q0 = pq[rb], q1 = pq[rb+1], q2 = pq[rb+2];
  float e0 = dq[rb], e1 = dq[rb+1], e2 = dq[rb+2];
  vnlk(q0, q1, q2, e0, e1, e2, sQ, shQ);
  float qn2 = q0*q0 + q1*q1 + q2*q2;
  float qsc = chnorm_sc(__builtin_amdgcn_sqrtf(qn2),
                        __builtin_amdgcn_sqrtf(wred_sum(qn2)));
  float qx0 = q0*qsc, qx1 = q1*qsc, qx2 = q2*qsc;
  float wk0 = wK[rb],  wk1 = wK[rb+1],  wk2 = wK[rb+2];
  float wdk0= wDk[rb], wdk1= wDk[rb+1], wdk2= wDk[rb+2];
  const float isq = 0.07216878364870323f;   // 1/sqrt(3*C)
  // ---- pass A: K branch -> qk[16]  (bundle seg0=uK, seg1=uDk)
  float qk[16];
  #pragma unroll
  for (int kk = 0; kk < 16; ++kk) {
    size_t gb = (size_t)(bN + mi[kk])*768 + o*3;
    float p0 = GB[gb]     + wk0, p1 = GB[gb+1]   + wk1, p2 = GB[gb+2]   + wk2;
    float f0 = GB[gb+192] + wdk0, f1 = GB[gb+193] + wdk1, f2 = GB[gb+194] + wdk2;
    vnlk(p0, p1, p2, f0, f1, f2, sK, shK);
    float nc2 = p0*p0 + p1*p1 + p2*p2;
    float sc = chnorm_sc(__builtin_amdgcn_sqrtf(nc2),
                         __builtin_amdgcn_sqrtf(wred_sum(nc2)));
    qk[kk] = (p0*qx0 + p1*qx1 + p2*qx2) * (sc * isq);
  }
  // ---- softmax over 16 in registers
  float mx = qk[0];
  #pragma unroll
  for (int kk = 1; kk < 16; ++kk) mx = fmaxf(mx, qk[kk]);
  float se = 0.f;
  #pragma unroll
  for (int kk = 0; kk < 16; ++kk) { float e = __expf(qk[kk] - mx); qk[kk] = e; se += e; }
  float inv = __builtin_amdgcn_rcpf(se);
  // ---- pass B: V branch (bundle seg2=uV, seg3=uDv), weighted accumulate
  float wv0 = wV[rb],  wv1 = wV[rb+1],  wv2 = wV[rb+2];
  float wdv0= wDv[rb], wdv1= wDv[rb+1], wdv2= wDv[rb+2];
  float a0 = 0.f, a1 = 0.f, a2 = 0.f;
  #pragma unroll
  for (int kk = 0; kk < 16; ++kk) {
    size_t gb = (size_t)(bN + mi[kk])*768 + o*3;
    float v0 = GB[gb+384] + wv0, v1 = GB[gb+385] + wv1, v2 = GB[gb+386] + wv2;
    float g0 = GB[gb+576] + wdv0, g1 = GB[gb+577] + wdv1, g2 = GB[gb+578] + wdv2;
    vnlk(v0, v1, v2, g0, g1, g2, sV, shV);
    float at = qk[kk] * inv;
    a0 = fmaf(at, v0, a0); a1 = fmaf(at, v1, a1); a2 = fmaf(at, v2, a2);
  }
  ob2[o*3 + 0][w] = a0;
  ob2[o*3 + 1][w] = a1;
  ob2[o*3 + 2][w] = a2;
  __syncthreads();
  if (t < 192) {                          // t == c*3+v; 4 consecutive n per row
    size_t xo = ((size_t)b*D3 + t)*N_ + n0;
    float4 xr = *(const float4*)&x[xo];
    float4 r;
    r.x = xr.x + ob2[t][0]; r.y = xr.y + ob2[t][1];
    r.z = xr.z + ob2[t][2]; r.w = xr.w + ob2[t][3];
    *(float4*)&out[xo] = r;
  }
}

extern "C" void kernel_launch(void* const* d_in, const int* in_sizes, int n_in,
                              void* d_out, int out_size, void* d_ws, size_t ws_size,
                              hipStream_t stream) {
  const float* x  = (const float*)d_in[0];
  const float* y  = (const float*)d_in[1];
  const float* Wq = (const float*)d_in[2];
  const float* Dq = (const float*)d_in[3];
  const float* gq = (const float*)d_in[4];
  const float* bq = (const float*)d_in[5];
  const float* Wk = (const float*)d_in[6];
  const float* Dk = (const float*)d_in[7];
  const float* gk = (const float*)d_in[8];
  const float* bk = (const float*)d_in[9];
  const float* Wv = (const float*)d_in[10];
  const float* Dv = (const float*)d_in[11];
  const float* gv = (const float*)d_in[12];
  const float* bv = (const float*)d_in[13];
  float* ws = (float*)d_ws;
  float* out = (float*)d_out;
  int* idxp = (int*)(ws + OFF_IDX);

  // batched kNN if the workspace can hold B full NxN dist buffers (~130 MB)
  const size_t need = (OFF_DIST + (size_t)B_*N_*N_) * sizeof(float);
  const bool batched = ws_size >= need;

  hipMemsetAsync((void*)(ws + OFF_ST), 0, 1024 * sizeof(float), stream);
  transform_kernel<<<dim3(N_/32, B_, 6), 256, 0, stream>>>(x, y, Wq, Dq, Wk, Dk, Wv, Dv, ws);
  if (batched) {
    dist_kernel<<<dim3(N_/256, N_/128, B_), 256, 0, stream>>>(y, ws, 0, (size_t)N_*N_);
    topk_kernel<<<dim3(N_/4, B_), 256, 0, stream>>>(ws, idxp, 0, (size_t)N_*N_);
  } else {
    for (int b = 0; b < B_; ++b) {
      dist_kernel<<<dim3(N_/256, N_/128, 1), 256, 0, stream>>>(y, ws, b, 0);
      topk_kernel<<<dim3(N_/4, 1), 256, 0, stream>>>(ws, idxp, b, 0);
    }
  }
  kvstats_kernel<<<dim3(N_*K_/128, B_), 256, 0, stream>>>(ws, idxp);
  final_kernel<<<dim3(N_/4, B_), 256, 0, stream>>>(x, ws, idxp, gq, bq, gk, bk, gv, bv, out);
}